// Round 14
// baseline (607.366 us; speedup 1.0000x reference)
//
#include <hip/hip_runtime.h>
#include <stdint.h>

typedef unsigned short u16;
typedef __bf16 bf16x8 __attribute__((ext_vector_type(8)));
typedef float f32x4 __attribute__((ext_vector_type(4)));

// ---------------------------------------------------------------------------
// EideticPhysicsAttention: N=65536 tokens, HID=512, H=8 heads, D=64, G=64.
//   conv  : split f32 -> (hi,lo) bf16 planes for W_x only (tiny)
//   K1    gemm_fA    : xp = x @ W_x.T + b_x ; A read f32 direct-from-global,
//                      converted to split-bf16 in registers -> packed u32 out
//   K2    k2_route   : MFMA logits+t1, threefry-gumbel, softmax -> wcat
//                      packed u32 (per-wave wbuf, NO block barriers in loop)
//   K3    k3_pool    : MFMA pooling: tok_num[h,g,d] = sum_n w*x ; nrm
//   K4a   k4_attn    : per-head 64-token attention -> o[h,g,d]
//   K4b   k4b_m2     : M2T[j][hg] hi/lo = sum_d o[hg][d]*W_out[j][h*64+d]
//   K5    gemm_packA : out = wcat @ M2T.T + b_out      (overwrites d_out)
// ---------------------------------------------------------------------------

__device__ __forceinline__ u16 f2bf(float f) {   // RNE bf16
  uint32_t u = __float_as_uint(f);
  uint32_t r = u + 0x7fffu + ((u >> 16) & 1u);
  return (u16)(r >> 16);
}
__device__ __forceinline__ float bf2f(u16 h) {
  return __uint_as_float(((uint32_t)h) << 16);
}

union BF8 { bf16x8 v; u16 u[8]; uint4 q4; };

__device__ __forceinline__ float gelu_fast(float x) {
  const float c = 0.79788456080286535588f;
  float z = c * fmaf(0.044715f, x * x * x, x);
  return x / (1.0f + __expf(-2.0f * z));
}

__device__ __forceinline__ uint32_t rotl32(uint32_t v, int s) {
  return (v << s) | (v >> (32 - s));
}

// JAX threefry2x32, key=(0,1) from jax.random.key(1), partitionable path.
__device__ __forceinline__ uint32_t threefry_bits(uint32_t idx) {
  const uint32_t k0 = 0u, k1 = 1u;
  const uint32_t k2 = 0x1BD11BDAu ^ k0 ^ k1;
  uint32_t x0 = 0u + k0;
  uint32_t x1 = idx + k1;
#define TF_R(r) { x0 += x1; x1 = rotl32(x1, r); x1 ^= x0; }
  TF_R(13) TF_R(15) TF_R(26) TF_R(6)
  x0 += k1; x1 += k2 + 1u;
  TF_R(17) TF_R(29) TF_R(16) TF_R(24)
  x0 += k2; x1 += k0 + 2u;
  TF_R(13) TF_R(15) TF_R(26) TF_R(6)
  x0 += k0; x1 += k1 + 3u;
  TF_R(17) TF_R(29) TF_R(16) TF_R(24)
  x0 += k1; x1 += k2 + 4u;
  TF_R(13) TF_R(15) TF_R(26) TF_R(6)
  x0 += k2; x1 += k0 + 5u;
#undef TF_R
  return x0 ^ x1;
}

__device__ __forceinline__ void gload_lds16(const void* g, void* l) {
  __builtin_amdgcn_global_load_lds(
      (const __attribute__((address_space(1))) void*)g,
      (__attribute__((address_space(3))) void*)l, 16, 0, 0);
}

// ---------------------------------------------------------------------------
// conv_split: f32 -> hi/lo bf16 planes (W_x only; 65536 float4 quads)
// ---------------------------------------------------------------------------
__global__ __launch_bounds__(256) void conv_split(
    const float* __restrict__ in, u16* __restrict__ hi, u16* __restrict__ lo,
    int nq)
{
  for (int i = blockIdx.x * 256 + threadIdx.x; i < nq; i += gridDim.x * 256) {
    float4 v = ((const float4*)in)[i];
    ushort4 h, l;
    h.x = f2bf(v.x); l.x = f2bf(v.x - bf2f(h.x));
    h.y = f2bf(v.y); l.y = f2bf(v.y - bf2f(h.y));
    h.z = f2bf(v.z); l.z = f2bf(v.z - bf2f(h.z));
    h.w = f2bf(v.w); l.w = f2bf(v.w - bf2f(h.w));
    ((ushort4*)hi)[i] = h;
    ((ushort4*)lo)[i] = l;
  }
}

// ---------------------------------------------------------------------------
// gemm_fA: Cp[m][j] = pack( sum_k x[m][k]*(Bh+Bl)[j][k] + bias[j] )
// A = f32 x, read DIRECT from global into fragments, converted to split-bf16
// in registers (bit-identical to conv_split's f2bf planes). B staged in LDS.
// 128x128 tile, BK=32, 4 waves, 3-term MFMA, XCD swizzle, packed u32 out.
// ---------------------------------------------------------------------------
__global__ __launch_bounds__(256) void gemm_fA(
    const float* __restrict__ A, const u16* __restrict__ Bh,
    const u16* __restrict__ Bl, const float* __restrict__ bias,
    uint32_t* __restrict__ Cp)
{
  __shared__ u16 ldsBh[128 * 32], ldsBl[128 * 32];   // 8 + 8 KB
  const int tid = threadIdx.x;
  const int lane = tid & 63;
  const int w = tid >> 6;
  const int vid = (blockIdx.x & 7) * 256 + (blockIdx.x >> 3);  // XCD swizzle
  const int bn = vid & 3;
  const int bm = vid >> 2;
  const int wr = w >> 1, wc = w & 1;

  f32x4 acc[4][4];
#pragma unroll
  for (int m = 0; m < 4; ++m)
#pragma unroll
    for (int n = 0; n < 4; ++n) acc[m][n] = (f32x4){0.f, 0.f, 0.f, 0.f};

  const int co = (lane >> 4) * 8;
  const int rr = lane & 15;

  for (int kt = 0; kt < 16; ++kt) {
    const int k0 = kt * 32;
    __syncthreads();
    // stage B planes: 8 row-blocks of 16 rows each per plane, 4 issues/wave
#pragma unroll
    for (int i = 0; i < 4; ++i) {
      const int plane = i >> 1;
      const int rb16 = (i & 1) * 4 + w;
      const int row = rb16 * 16 + (lane >> 2);
      const int sc = (lane & 3) * 8;
      const u16* src = ((plane == 0) ? Bh : Bl)
                       + (size_t)(bn * 128 + row) * 512 + k0 + sc;
      gload_lds16(src, (plane == 0) ? &ldsBh[rb16 * 16 * 32]
                                    : &ldsBl[rb16 * 16 * 32]);
    }
    // load A f32 fragments direct from global
    float4 a0[4], a1[4];
#pragma unroll
    for (int f = 0; f < 4; ++f) {
      const float* ap = A + (size_t)(bm * 128 + wr * 64 + f * 16 + rr) * 512
                        + k0 + co;
      a0[f] = *(const float4*)ap;
      a1[f] = *(const float4*)(ap + 4);
    }
    // convert to split bf16 (same f2bf math as conv_split -> bit-identical)
    bf16x8 ah[4], al[4];
#pragma unroll
    for (int f = 0; f < 4; ++f) {
      const float vv[8] = {a0[f].x, a0[f].y, a0[f].z, a0[f].w,
                           a1[f].x, a1[f].y, a1[f].z, a1[f].w};
      BF8 hv, lv;
#pragma unroll
      for (int e = 0; e < 8; ++e) {
        const u16 hb = f2bf(vv[e]);
        hv.u[e] = hb;
        lv.u[e] = f2bf(vv[e] - bf2f(hb));
      }
      ah[f] = hv.v; al[f] = lv.v;
    }
    __syncthreads();

    bf16x8 bh_[4], bl_[4];
#pragma unroll
    for (int f = 0; f < 4; ++f) {
      const int rb2 = (wc * 64 + f * 16 + rr) * 32 + co;
      bh_[f] = *(const bf16x8*)&ldsBh[rb2];
      bl_[f] = *(const bf16x8*)&ldsBl[rb2];
    }
#pragma unroll
    for (int m = 0; m < 4; ++m)
#pragma unroll
      for (int n = 0; n < 4; ++n) {
        acc[m][n] = __builtin_amdgcn_mfma_f32_16x16x32_bf16(ah[m], bh_[n], acc[m][n], 0, 0, 0);
        acc[m][n] = __builtin_amdgcn_mfma_f32_16x16x32_bf16(ah[m], bl_[n], acc[m][n], 0, 0, 0);
        acc[m][n] = __builtin_amdgcn_mfma_f32_16x16x32_bf16(al[m], bh_[n], acc[m][n], 0, 0, 0);
      }
  }

  const int cn0 = lane & 15;
  const int rm0 = (lane >> 4) * 4;
#pragma unroll
  for (int n = 0; n < 4; ++n) {
    const int ng = bn * 128 + wc * 64 + n * 16 + cn0;
    const float bv = bias[ng];
#pragma unroll
    for (int m = 0; m < 4; ++m) {
      const int mg = bm * 128 + wr * 64 + m * 16 + rm0;
#pragma unroll
      for (int r = 0; r < 4; ++r) {
        const float v = acc[m][n][r] + bv;
        const u16 hb = f2bf(v);
        const u16 lb = f2bf(v - bf2f(hb));
        Cp[(size_t)(mg + r) * 512 + ng] = (uint32_t)hb | ((uint32_t)lb << 16);
      }
    }
  }
}

// ---------------------------------------------------------------------------
// gemm_packA: A PACKED u32 (hi|lo<<16); B hi/lo u16 planes; C = f32 out.
// ---------------------------------------------------------------------------
__global__ __launch_bounds__(256) void gemm_packA(
    const uint32_t* __restrict__ A, const u16* __restrict__ Bh,
    const u16* __restrict__ Bl, const float* __restrict__ bias,
    float* __restrict__ C)
{
  __shared__ uint32_t ldsA[128 * 32];              // 16 KB
  __shared__ u16 ldsBh[128 * 32], ldsBl[128 * 32]; // 8 + 8 KB
  const int tid = threadIdx.x;
  const int lane = tid & 63;
  const int w = tid >> 6;
  const int vid = (blockIdx.x & 7) * 256 + (blockIdx.x >> 3);  // XCD swizzle
  const int bn = vid & 3;
  const int bm = vid >> 2;
  const int wr = w >> 1, wcq = w & 1;

  f32x4 acc[4][4];
#pragma unroll
  for (int m = 0; m < 4; ++m)
#pragma unroll
    for (int n = 0; n < 4; ++n) acc[m][n] = (f32x4){0.f, 0.f, 0.f, 0.f};

  for (int kt = 0; kt < 16; ++kt) {
    const int k0 = kt * 32;
    __syncthreads();
#pragma unroll
    for (int i = 0; i < 4; ++i) {
      const int rb8 = i * 4 + w;
      const int row = rb8 * 8 + (lane >> 3);
      const uint32_t* src =
          A + (size_t)(bm * 128 + row) * 512 + k0 + (lane & 7) * 4;
      gload_lds16(src, &ldsA[rb8 * 8 * 32]);
    }
#pragma unroll
    for (int i = 0; i < 2; ++i) {
      const int rb16 = i * 4 + w;
      const int row = rb16 * 16 + (lane >> 2);
      const int sc = (lane & 3) * 8;
      gload_lds16(Bh + (size_t)(bn * 128 + row) * 512 + k0 + sc,
                  &ldsBh[rb16 * 16 * 32]);
      gload_lds16(Bl + (size_t)(bn * 128 + row) * 512 + k0 + sc,
                  &ldsBl[rb16 * 16 * 32]);
    }
    __syncthreads();

    bf16x8 ah[4], al[4], bh_[4], bl_[4];
    const int co = (lane >> 4) * 8;
    const int rr = lane & 15;
#pragma unroll
    for (int f = 0; f < 4; ++f) {
      const int ra = (wr * 64 + f * 16 + rr) * 32 + co;
      const uint4 p0 = *(const uint4*)&ldsA[ra];
      const uint4 p1 = *(const uint4*)&ldsA[ra + 4];
      BF8 hv, lv;
      uint32_t* hd = (uint32_t*)&hv.q4;
      uint32_t* ld = (uint32_t*)&lv.q4;
      hd[0] = __builtin_amdgcn_perm(p0.y, p0.x, 0x05040100u);
      hd[1] = __builtin_amdgcn_perm(p0.w, p0.z, 0x05040100u);
      hd[2] = __builtin_amdgcn_perm(p1.y, p1.x, 0x05040100u);
      hd[3] = __builtin_amdgcn_perm(p1.w, p1.z, 0x05040100u);
      ld[0] = __builtin_amdgcn_perm(p0.y, p0.x, 0x07060302u);
      ld[1] = __builtin_amdgcn_perm(p0.w, p0.z, 0x07060302u);
      ld[2] = __builtin_amdgcn_perm(p1.y, p1.x, 0x07060302u);
      ld[3] = __builtin_amdgcn_perm(p1.w, p1.z, 0x07060302u);
      ah[f] = hv.v; al[f] = lv.v;
      const int rb2 = (wcq * 64 + f * 16 + rr) * 32 + co;
      bh_[f] = *(const bf16x8*)&ldsBh[rb2];
      bl_[f] = *(const bf16x8*)&ldsBl[rb2];
    }
#pragma unroll
    for (int m = 0; m < 4; ++m)
#pragma unroll
      for (int n = 0; n < 4; ++n) {
        acc[m][n] = __builtin_amdgcn_mfma_f32_16x16x32_bf16(ah[m], bh_[n], acc[m][n], 0, 0, 0);
        acc[m][n] = __builtin_amdgcn_mfma_f32_16x16x32_bf16(ah[m], bl_[n], acc[m][n], 0, 0, 0);
        acc[m][n] = __builtin_amdgcn_mfma_f32_16x16x32_bf16(al[m], bh_[n], acc[m][n], 0, 0, 0);
      }
  }

  const int cn0 = lane & 15;
  const int rm0 = (lane >> 4) * 4;
#pragma unroll
  for (int n = 0; n < 4; ++n) {
    const int ng = bn * 128 + wcq * 64 + n * 16 + cn0;
    const float bv = bias[ng];
#pragma unroll
    for (int m = 0; m < 4; ++m) {
      const int mg = bm * 128 + wr * 64 + m * 16 + rm0;
#pragma unroll
      for (int r = 0; r < 4; ++r)
        C[(size_t)(mg + r) * 512 + ng] = acc[m][n][r] + bv;
    }
  }
}

// ---------------------------------------------------------------------------
// K2: MFMA routing; xp read PACKED (A-frags via v_perm). Per-wave LDS
// transpose -> coalesced packed u32 stores. wbuf is strictly per-wave, so
// the tm loop has NO block barriers (intra-wave lgkmcnt orders wbuf).
// ---------------------------------------------------------------------------
__global__ __launch_bounds__(256, 4) void k2_route(
    const uint32_t* __restrict__ xpq, const float* __restrict__ Wsl,
    const float* __restrict__ bsl, const float* __restrict__ Wt1,
    const float* __restrict__ bt1, const float* __restrict__ Wt2,
    const float* __restrict__ bt2, const float* __restrict__ tbias,
    uint32_t* __restrict__ wcp)
{
  __shared__ u16 Wf[2][8][2][64][8];      // frag-ordered W planes, 32 KB
  __shared__ uint32_t wbuf[4][16][68];    // per-wave transpose, hi|lo<<16

  const int tid = threadIdx.x;
  const int l = tid & 63, wid = tid >> 6;
  const int l15 = l & 15, q = l >> 4;
  const int h = blockIdx.x >> 8;
  const int chunk = blockIdx.x & 255;

  // ---- stage W fragments (once per block) ----
#pragma unroll
  for (int it = 0; it < 8; ++it) {
    const int slot = tid + it * 256;
    const int p = slot >> 10;
    const int rest = slot & 1023;
    const int nn = rest >> 7;
    const int kk = (rest >> 6) & 1;
    const int sl = rest & 63;
    const int row = nn * 16 + (sl & 15);
    const int kb = kk * 32 + (sl >> 4) * 8;
    const float* src = (row < 64) ? (Wsl + row * 64 + kb)
                                  : (Wt1 + (row - 64) * 64 + kb);
#pragma unroll
    for (int e = 0; e < 8; ++e) {
      const float v = src[e];
      const u16 hb = f2bf(v);
      Wf[p][nn][kk][sl][e] = (p == 0) ? hb : f2bf(v - bf2f(hb));
    }
  }
  __syncthreads();

  float bslv[4], bt1v[4], wt2v[4];
#pragma unroll
  for (int j = 0; j < 4; ++j) {
    bslv[j] = bsl[j * 16 + l15];
    bt1v[j] = bt1[j * 16 + l15];
    wt2v[j] = Wt2[j * 16 + l15];
  }
  const float bt2v = bt2[0], tbv = tbias[h];

#pragma unroll 1
  for (int tm = 0; tm < 4; ++tm) {
    const int n0t = chunk * 256 + (tm >> 1) * 128 + wid * 32 + (tm & 1) * 16;

    // ---- A fragments from packed xp via v_perm ----
    bf16x8 ah[2], al[2];
#pragma unroll
    for (int kk = 0; kk < 2; ++kk) {
      const uint32_t* sp = xpq + (size_t)(n0t + l15) * 512 + h * 64
                           + kk * 32 + q * 8;
      const uint4 p0 = *(const uint4*)sp;
      const uint4 p1 = *(const uint4*)(sp + 4);
      BF8 hv, lv;
      uint32_t* hd = (uint32_t*)&hv.q4;
      uint32_t* ld = (uint32_t*)&lv.q4;
      hd[0] = __builtin_amdgcn_perm(p0.y, p0.x, 0x05040100u);
      hd[1] = __builtin_amdgcn_perm(p0.w, p0.z, 0x05040100u);
      hd[2] = __builtin_amdgcn_perm(p1.y, p1.x, 0x05040100u);
      hd[3] = __builtin_amdgcn_perm(p1.w, p1.z, 0x05040100u);
      ld[0] = __builtin_amdgcn_perm(p0.y, p0.x, 0x07060302u);
      ld[1] = __builtin_amdgcn_perm(p0.w, p0.z, 0x07060302u);
      ld[2] = __builtin_amdgcn_perm(p1.y, p1.x, 0x07060302u);
      ld[3] = __builtin_amdgcn_perm(p1.w, p1.z, 0x07060302u);
      ah[kk] = hv.v; al[kk] = lv.v;
    }

    // ---- MFMA: [16 tok] x [128 cols], K=64, 3-term ----
    f32x4 acc[8];
#pragma unroll
    for (int n = 0; n < 8; ++n) acc[n] = (f32x4){0.f, 0.f, 0.f, 0.f};
#pragma unroll
    for (int kk = 0; kk < 2; ++kk)
#pragma unroll
      for (int nn = 0; nn < 8; ++nn) {
        BF8 whf, wlf;
        whf.q4 = *(const uint4*)&Wf[0][nn][kk][l][0];
        wlf.q4 = *(const uint4*)&Wf[1][nn][kk][l][0];
        acc[nn] = __builtin_amdgcn_mfma_f32_16x16x32_bf16(ah[kk], whf.v, acc[nn], 0, 0, 0);
        acc[nn] = __builtin_amdgcn_mfma_f32_16x16x32_bf16(ah[kk], wlf.v, acc[nn], 0, 0, 0);
        acc[nn] = __builtin_amdgcn_mfma_f32_16x16x32_bf16(al[kk], whf.v, acc[nn], 0, 0, 0);
      }

    // ---- temperature per r ----
    float itv[4];
#pragma unroll
    for (int r = 0; r < 4; ++r) {
      float part = 0.f;
#pragma unroll
      for (int j = 0; j < 4; ++j)
        part += gelu_fast(acc[4 + j][r] + bt1v[j]) * wt2v[j];
      part += __shfl_xor(part, 1);
      part += __shfl_xor(part, 2);
      part += __shfl_xor(part, 4);
      part += __shfl_xor(part, 8);
      const float tval = gelu_fast(part + bt2v) + tbv;
      itv[r] = 1.0f / fmaxf(tval, 0.01f);
    }

    // ---- logits: bias + threefry-gumbel + /t ----
    const uint32_t pbase = ((uint32_t)((h << 16) | (n0t + q * 4))) << 6;
#pragma unroll
    for (int j = 0; j < 4; ++j) {
      const uint32_t cc = j * 16 + l15;
#pragma unroll
      for (int r = 0; r < 4; ++r) {
        const uint32_t bits = threefry_bits(pbase + ((uint32_t)r << 6) + cc);
        const float u = __uint_as_float((bits >> 9) | 0x3f800000u) - 1.0f;
        const float gin = -__logf(u + 1e-8f);
        const float gn = -__logf(gin + 1e-8f);
        acc[j][r] = (acc[j][r] + bslv[j] + gn) * itv[r];
      }
    }

    // ---- softmax over cols ----
#pragma unroll
    for (int r = 0; r < 4; ++r) {
      float mx = fmaxf(fmaxf(acc[0][r], acc[1][r]),
                       fmaxf(acc[2][r], acc[3][r]));
      mx = fmaxf(mx, __shfl_xor(mx, 1));
      mx = fmaxf(mx, __shfl_xor(mx, 2));
      mx = fmaxf(mx, __shfl_xor(mx, 4));
      mx = fmaxf(mx, __shfl_xor(mx, 8));
      float se = 0.f;
#pragma unroll
      for (int j = 0; j < 4; ++j) {
        const float e = __expf(acc[j][r] - mx);
        acc[j][r] = e;
        se += e;
      }
      se += __shfl_xor(se, 1);
      se += __shfl_xor(se, 2);
      se += __shfl_xor(se, 4);
      se += __shfl_xor(se, 8);
      const float inv = 1.0f / se;
#pragma unroll
      for (int j = 0; j < 4; ++j) acc[j][r] *= inv;
    }

    // ---- pack hi|lo into per-wave LDS transpose (wave-private; no barrier)
#pragma unroll
    for (int j = 0; j < 4; ++j)
#pragma unroll
      for (int r = 0; r < 4; ++r) {
        const float wv = acc[j][r];
        const u16 hb = f2bf(wv);
        const u16 lb = f2bf(wv - bf2f(hb));
        wbuf[wid][q * 4 + r][j * 16 + l15] = (uint32_t)hb | ((uint32_t)lb << 16);
      }

    // ---- coalesced packed stores: 16 tok x 16 uint4 -> 64 lanes x 4 ----
#pragma unroll
    for (int it = 0; it < 4; ++it) {
      const int t = l >> 2;
      const int qq = (l & 3) + it * 4;    // 0..15
      const uint4 v = *(const uint4*)&wbuf[wid][t][qq * 4];
      *(uint4*)(wcp + (size_t)(n0t + t) * 512 + h * 64 + qq * 4) = v;
    }
  }
}

// ---------------------------------------------------------------------------
// K3: MFMA pooling. Per head: tok_num[g,d] = sum_n w[n,g]*x[n,d] (K=65536).
// Grid = 8 heads x 64 chunks (1024 tok); 4 waves x 256 tok; per wave 8 tiles
// of 32 tokens. Fragment gathers straight from global. 3-term split-bf16.
// ---------------------------------------------------------------------------
__global__ __launch_bounds__(256, 2) void k3_pool(
    const uint32_t* __restrict__ xpq, const uint32_t* __restrict__ wcp,
    float* __restrict__ tok_num, float* __restrict__ nrm)
{
  __shared__ float red[64][65];
  const int h = blockIdx.x >> 6;
  const int chunk = blockIdx.x & 63;
  const int lane = threadIdx.x & 63;
  const int wid = threadIdx.x >> 6;
  const int l15 = lane & 15, q = lane >> 4;

  f32x4 acc[4][4];
#pragma unroll
  for (int m = 0; m < 4; ++m)
#pragma unroll
    for (int n = 0; n < 4; ++n) acc[m][n] = (f32x4){0.f, 0.f, 0.f, 0.f};
  float csum[4] = {0.f, 0.f, 0.f, 0.f};

  const int tw = chunk * 1024 + wid * 256;
#pragma unroll 1
  for (int tt = 0; tt < 8; ++tt) {
    const int t0 = tw + tt * 32;
    uint32_t wreg[4][8], xreg[4][8];
#pragma unroll
    for (int e = 0; e < 8; ++e) {
      const size_t rb = (size_t)(t0 + q * 8 + e) * 512 + h * 64 + l15;
#pragma unroll
      for (int m = 0; m < 4; ++m) {
        wreg[m][e] = wcp[rb + m * 16];
        xreg[m][e] = xpq[rb + m * 16];
      }
    }
    bf16x8 whf[4], wlf[4], xhf[4], xlf[4];
#pragma unroll
    for (int m = 0; m < 4; ++m) {
      BF8 hv, lv, xh, xl;
      uint32_t* hd = (uint32_t*)&hv.q4;
      uint32_t* ld = (uint32_t*)&lv.q4;
      uint32_t* xhd = (uint32_t*)&xh.q4;
      uint32_t* xld = (uint32_t*)&xl.q4;
#pragma unroll
      for (int p = 0; p < 4; ++p) {
        hd[p]  = __builtin_amdgcn_perm(wreg[m][2*p+1], wreg[m][2*p], 0x05040100u);
        ld[p]  = __builtin_amdgcn_perm(wreg[m][2*p+1], wreg[m][2*p], 0x07060302u);
        xhd[p] = __builtin_amdgcn_perm(xreg[m][2*p+1], xreg[m][2*p], 0x05040100u);
        xld[p] = __builtin_amdgcn_perm(xreg[m][2*p+1], xreg[m][2*p], 0x07060302u);
      }
      whf[m] = hv.v; wlf[m] = lv.v; xhf[m] = xh.v; xlf[m] = xl.v;
#pragma unroll
      for (int e = 0; e < 8; ++e)
        csum[m] += __uint_as_float(wreg[m][e] << 16)
                 + __uint_as_float(wreg[m][e] & 0xffff0000u);
    }
#pragma unroll
    for (int m = 0; m < 4; ++m)
#pragma unroll
      for (int n = 0; n < 4; ++n) {
        acc[m][n] = __builtin_amdgcn_mfma_f32_16x16x32_bf16(whf[m], xhf[n], acc[m][n], 0, 0, 0);
        acc[m][n] = __builtin_amdgcn_mfma_f32_16x16x32_bf16(whf[m], xlf[n], acc[m][n], 0, 0, 0);
        acc[m][n] = __builtin_amdgcn_mfma_f32_16x16x32_bf16(wlf[m], xhf[n], acc[m][n], 0, 0, 0);
      }
  }

  // nrm: reduce csum over q-groups, lanes q==0 add 4 g-values each
#pragma unroll
  for (int m = 0; m < 4; ++m) {
    csum[m] += __shfl_xor(csum[m], 16);
    csum[m] += __shfl_xor(csum[m], 32);
  }
  if (q == 0) {
#pragma unroll
    for (int m = 0; m < 4; ++m)
      atomicAdd(&nrm[h * 64 + m * 16 + l15], csum[m]);
  }

  // cross-wave reduce
  for (int w = 0; w < 4; ++w) {
    if (wid == w) {
#pragma unroll
      for (int m = 0; m < 4; ++m)
#pragma unroll
        for (int n = 0; n < 4; ++n)
#pragma unroll
          for (int r = 0; r < 4; ++r) {
            const int g = m * 16 + q * 4 + r;
            const int d = n * 16 + l15;
            if (w == 0) red[g][d] = acc[m][n][r];
            else        red[g][d] += acc[m][n][r];
          }
    }
    __syncthreads();
  }
  for (int e = threadIdx.x; e < 4096; e += 256)
    atomicAdd(&tok_num[h * 4096 + e], red[e >> 6][e & 63]);
}

// ---------------------------------------------------------------------------
// K4a: per-head attention over G=64 slice tokens. One block per head.
// ---------------------------------------------------------------------------
__global__ __launch_bounds__(256) void k4_attn(
    const float* __restrict__ tok_num, const float* __restrict__ nrm,
    const float* __restrict__ Wq, const float* __restrict__ Wk,
    const float* __restrict__ Wv, const float* __restrict__ Wo,
    float* __restrict__ o_out)
{
  __shared__ float T[64][65], Abuf[64][65], Bbuf[64][65], Wbuf[64][65], S2[64][65];
  const int h = blockIdx.x;
  const int tid = threadIdx.x;

  for (int e = tid; e < 4096; e += 256) {
    const int g = e >> 6, d = e & 63;
    T[g][d] = tok_num[h * 4096 + e] / (nrm[h * 64 + g] + 1e-5f);
  }
  for (int e = tid; e < 4096; e += 256) Wbuf[e >> 6][e & 63] = Wq[e];
  __syncthreads();

  const int g = tid >> 2, d0 = (tid & 3) * 16;
  float r[16];

#pragma unroll
  for (int j = 0; j < 16; ++j) r[j] = 0.f;
  for (int e = 0; e < 64; ++e) {
    const float tv = T[g][e];
#pragma unroll
    for (int j = 0; j < 16; ++j) r[j] = fmaf(tv, Wbuf[d0 + j][e], r[j]);
  }
#pragma unroll
  for (int j = 0; j < 16; ++j) Abuf[g][d0 + j] = r[j];
  __syncthreads();

  for (int e = tid; e < 4096; e += 256) Wbuf[e >> 6][e & 63] = Wk[e];
  __syncthreads();

#pragma unroll
  for (int j = 0; j < 16; ++j) r[j] = 0.f;
  for (int e = 0; e < 64; ++e) {
    const float tv = T[g][e];
#pragma unroll
    for (int j = 0; j < 16; ++j) r[j] = fmaf(tv, Wbuf[d0 + j][e], r[j]);
  }
#pragma unroll
  for (int j = 0; j < 16; ++j) Bbuf[g][d0 + j] = r[j];
  __syncthreads();

#pragma unroll
  for (int j = 0; j < 16; ++j) r[j] = 0.f;
  for (int e = 0; e < 64; ++e) {
    const float qv = Abuf[g][e] * 0.125f;
#pragma unroll
    for (int j = 0; j < 16; ++j) r[j] = fmaf(qv, Bbuf[d0 + j][e], r[j]);
  }
#pragma unroll
  for (int j = 0; j < 16; ++j) S2[g][d0 + j] = r[j];
  __syncthreads();

  if (tid < 64) {
    float mx = -1e30f;
    for (int j = 0; j < 64; ++j) mx = fmaxf(mx, S2[tid][j]);
    float sum = 0.f;
    for (int j = 0; j < 64; ++j) {
      const float e2 = expf(S2[tid][j] - mx);
      S2[tid][j] = e2;
      sum += e2;
    }
    const float inv = 1.0f / sum;
    for (int j = 0; j < 64; ++j) S2[tid][j] *= inv;
  }
  __syncthreads();

  for (int e = tid; e < 4096; e += 256) Wbuf[e >> 6][e & 63] = Wv[e];
  __syncthreads();

#pragma unroll
  for (int j = 0; j < 16; ++j) r[j] = 0.f;
  for (int e = 0; e < 64; ++e) {
    const float tv = T[g][e];
#pragma unroll
    for (int j = 0; j < 16; ++j) r[j] = fmaf(tv, Wbuf[d0 + j][e], r[j]);
  }
  __syncthreads();
#pragma unroll
  for (int j = 0; j < 16; ++j) Bbuf[g][d0 + j] = r[j];
  __syncthreads();

#pragma unroll
  for (int j = 0; j < 16; ++j) r[j] = 0.f;
  for (int e = 0; e < 64; ++e) {
    const float sv = S2[g][e];
#pragma unroll
    for (int j = 0; j < 16; ++j) r[j] = fmaf(sv, Bbuf[e][d0 + j], r[j]);
  }
  __syncthreads();
#pragma unroll
  for (int j = 0; j < 16; ++j) Abuf[g][d0 + j] = r[j];
  for (int e = tid; e < 4096; e += 256) Wbuf[e >> 6][e & 63] = Wo[e];
  __syncthreads();

#pragma unroll
  for (int j = 0; j < 16; ++j) r[j] = 0.f;
  for (int e = 0; e < 64; ++e) {
    const float ov = Abuf[g][e];
#pragma unroll
    for (int j = 0; j < 16; ++j) r[j] = fmaf(ov, Wbuf[d0 + j][e], r[j]);
  }
#pragma unroll
  for (int j = 0; j < 16; ++j) o_out[h * 4096 + g * 64 + d0 + j] = r[j];
}

// ---------------------------------------------------------------------------
// K4b: M2T[j][hg] = sum_d o[hg][d] * W_out[j][h*64+d]  -> hi/lo bf16 planes
// ---------------------------------------------------------------------------
__global__ __launch_bounds__(256) void k4b_m2(
    const float* __restrict__ o, const float* __restrict__ Wout,
    u16* __restrict__ M2h, u16* __restrict__ M2l)
{
  const int j = blockIdx.x >> 1;
  const int hg = ((blockIdx.x & 1) << 8) + threadIdx.x;
  const int h = hg >> 6;
  const float* orow = &o[hg * 64];
  const float* wrow = &Wout[j * 512 + h * 64];
  float s = 0.f;
#pragma unroll
  for (int d = 0; d < 64; ++d) s = fmaf(orow[d], wrow[d], s);
  const u16 hb = f2bf(s);
  M2h[j * 512 + hg] = hb;
  M2l[j * 512 + hg] = f2bf(s - bf2f(hb));
}

// ---------------------------------------------------------------------------
extern "C" void kernel_launch(void* const* d_in, const int* in_sizes, int n_in,
                              void* d_out, int out_size, void* d_ws, size_t ws_size,
                              hipStream_t stream)
{
  const float* x      = (const float*)d_in[0];
  const float* W_x    = (const float*)d_in[1];
  const float* b_x    = (const float*)d_in[2];
  const float* W_sl   = (const float*)d_in[3];
  const float* b_sl   = (const float*)d_in[4];
  const float* W_t1   = (const float*)d_in[5];
  const float* b_t1   = (const float*)d_in[6];
  const float* W_t2   = (const float*)d_in[7];
  const float* b_t2   = (const float*)d_in[8];
  const float* t_bias = (const float*)d_in[9];
  const float* Wq     = (const float*)d_in[10];
  const float* Wk     = (const float*)d_in[11];
  const float* Wv     = (const float*)d_in[12];
  const float* Wo     = (const float*)d_in[13];
  const float* W_out  = (const float*)d_in[14];
  const float* b_out  = (const float*)d_in[15];

  float* out = (float*)d_out;
  uint32_t* xpq = (uint32_t*)d_out;  // packed xp lives in d_out until GEMM2

  char* ws = (char*)d_ws;
  uint32_t* wcp   = (uint32_t*)(ws);             // packed wcat (134 MB)
  u16*      Bhi   = (u16*)(ws + 134217728);      // Wx hi, then M2T hi
  u16*      Blo   = (u16*)(ws + 134742016);      // Wx lo, then M2T lo
  float* tok_num  = (float*)(ws + 135266304);    // 131072 B
  float* nrm      = (float*)(ws + 135397376);    // 2048 B
  float* o_buf    = (float*)(ws + 135399424);    // 131072 B

  conv_split<<<256, 256, 0, stream>>>(W_x, Bhi, Blo, 65536);
  gemm_fA<<<2048, 256, 0, stream>>>(x, Bhi, Blo, b_x, xpq);

  hipMemsetAsync(tok_num, 0, 133120, stream);  // tok_num + nrm (contiguous)

  k2_route<<<2048, 256, 0, stream>>>(xpq, W_sl, b_sl, W_t1, b_t1, W_t2, b_t2,
                                     t_bias, wcp);
  k3_pool<<<512, 256, 0, stream>>>(xpq, wcp, tok_num, nrm);
  k4_attn<<<8, 256, 0, stream>>>(tok_num, nrm, Wq, Wk, Wv, Wo, o_buf);
  k4b_m2<<<1024, 256, 0, stream>>>(o_buf, W_out, Bhi, Blo);    // overwrites Wx-split
  gemm_packA<<<2048, 256, 0, stream>>>(wcp, Bhi, Blo, b_out, out);
}

// Round 16
// 582.328 us; speedup vs baseline: 1.0430x; 1.0430x over previous
//
#include <hip/hip_runtime.h>
#include <stdint.h>

typedef unsigned short u16;
typedef __bf16 bf16x8 __attribute__((ext_vector_type(8)));
typedef float f32x4 __attribute__((ext_vector_type(4)));

// ---------------------------------------------------------------------------
// EideticPhysicsAttention: N=65536 tokens, HID=512, H=8 heads, D=64, G=64.
//   conv  : split f32 -> (hi,lo) bf16 planes for x and W_x
//   K1    gemm_split : xp = x @ W_x.T + b_x  -> PACKED u32 (hi|lo<<16) in d_out
//   K2    k2_route   : MFMA logits+t1, threefry-gumbel, softmax -> wcat
//                      packed u32 (per-wave wbuf, no block barriers in loop)
//   K3    k3_pool    : MFMA pooling: tok_num[h,g,d] = sum_n w*x ; nrm
//   K4a   k4_attn    : per-head 64-token attention -> o[h,g,d]
//   K4b   k4b_m2     : M2T[j][hg] hi/lo = sum_d o[hg][d]*W_out[j][h*64+d]
//   K5    gemm_packA : out = wcat @ M2T.T + b_out      (overwrites d_out)
// ---------------------------------------------------------------------------

__device__ __forceinline__ u16 f2bf(float f) {   // RNE bf16
  uint32_t u = __float_as_uint(f);
  uint32_t r = u + 0x7fffu + ((u >> 16) & 1u);
  return (u16)(r >> 16);
}
__device__ __forceinline__ float bf2f(u16 h) {
  return __uint_as_float(((uint32_t)h) << 16);
}

union BF8 { bf16x8 v; u16 u[8]; uint4 q4; };

__device__ __forceinline__ float gelu_fast(float x) {
  const float c = 0.79788456080286535588f;
  float z = c * fmaf(0.044715f, x * x * x, x);
  return x / (1.0f + __expf(-2.0f * z));
}

__device__ __forceinline__ uint32_t rotl32(uint32_t v, int s) {
  return (v << s) | (v >> (32 - s));
}

// JAX threefry2x32, key=(0,1) from jax.random.key(1), partitionable path.
__device__ __forceinline__ uint32_t threefry_bits(uint32_t idx) {
  const uint32_t k0 = 0u, k1 = 1u;
  const uint32_t k2 = 0x1BD11BDAu ^ k0 ^ k1;
  uint32_t x0 = 0u + k0;
  uint32_t x1 = idx + k1;
#define TF_R(r) { x0 += x1; x1 = rotl32(x1, r); x1 ^= x0; }
  TF_R(13) TF_R(15) TF_R(26) TF_R(6)
  x0 += k1; x1 += k2 + 1u;
  TF_R(17) TF_R(29) TF_R(16) TF_R(24)
  x0 += k2; x1 += k0 + 2u;
  TF_R(13) TF_R(15) TF_R(26) TF_R(6)
  x0 += k0; x1 += k1 + 3u;
  TF_R(17) TF_R(29) TF_R(16) TF_R(24)
  x0 += k1; x1 += k2 + 4u;
  TF_R(13) TF_R(15) TF_R(26) TF_R(6)
  x0 += k2; x1 += k0 + 5u;
#undef TF_R
  return x0 ^ x1;
}

__device__ __forceinline__ void gload_lds16(const void* g, void* l) {
  __builtin_amdgcn_global_load_lds(
      (const __attribute__((address_space(1))) void*)g,
      (__attribute__((address_space(3))) void*)l, 16, 0, 0);
}

// ---------------------------------------------------------------------------
// conv_split: f32 -> hi/lo bf16 planes (grid-stride over float4 quads)
// ---------------------------------------------------------------------------
__global__ __launch_bounds__(256) void conv_split(
    const float* __restrict__ in, u16* __restrict__ hi, u16* __restrict__ lo,
    int nq)
{
  for (int i = blockIdx.x * 256 + threadIdx.x; i < nq; i += gridDim.x * 256) {
    float4 v = ((const float4*)in)[i];
    ushort4 h, l;
    h.x = f2bf(v.x); l.x = f2bf(v.x - bf2f(h.x));
    h.y = f2bf(v.y); l.y = f2bf(v.y - bf2f(h.y));
    h.z = f2bf(v.z); l.z = f2bf(v.z - bf2f(h.z));
    h.w = f2bf(v.w); l.w = f2bf(v.w - bf2f(h.w));
    ((ushort4*)hi)[i] = h;
    ((ushort4*)lo)[i] = l;
  }
}

// ---------------------------------------------------------------------------
// gemm_split: Cp[m][j] = pack( sum_k (Ah+Al)[m][k]*(Bh+Bl)[j][k] + bias[j] )
// Output PACKED u32 (hi | lo<<16).  128x128 tile, BK=32, XCD swizzle.
// ---------------------------------------------------------------------------
__global__ __launch_bounds__(256) void gemm_split(
    const u16* __restrict__ Ah, const u16* __restrict__ Al,
    const u16* __restrict__ Bh, const u16* __restrict__ Bl,
    const float* __restrict__ bias, uint32_t* __restrict__ Cp)
{
  __shared__ u16 lds[4][4096];   // [Ah,Al,Bh,Bl][128 rows * 32 k] = 32 KB
  const int tid = threadIdx.x;
  const int lane = tid & 63;
  const int w = tid >> 6;
  const int vid = (blockIdx.x & 7) * 256 + (blockIdx.x >> 3);  // XCD swizzle
  const int bn = vid & 3;
  const int bm = vid >> 2;
  const int wr = w >> 1, wc = w & 1;

  f32x4 acc[4][4];
#pragma unroll
  for (int m = 0; m < 4; ++m)
#pragma unroll
    for (int n = 0; n < 4; ++n) acc[m][n] = (f32x4){0.f, 0.f, 0.f, 0.f};

  const int srow = lane >> 2;
  const int scol = (lane & 3) * 8;

  for (int kt = 0; kt < 16; ++kt) {
    const int k0 = kt * 32;
    __syncthreads();
#pragma unroll
    for (int i = 0; i < 8; ++i) {
      const int mat = i & 3;
      const int rb = w * 2 + (i >> 2);
      const int row = rb * 16 + srow;
      const u16* base = (mat == 0) ? Ah : (mat == 1) ? Al
                       : (mat == 2) ? Bh : Bl;
      const int tbase = (mat < 2) ? bm * 128 : bn * 128;
      const u16* src = base + (size_t)(tbase + row) * 512 + k0 + scol;
      gload_lds16(src, &lds[mat][rb * 512]);
    }
    __syncthreads();

    bf16x8 ah[4], al[4], bh_[4], bl_[4];
    const int co = (lane >> 4) * 8;
    const int rr = lane & 15;
#pragma unroll
    for (int f = 0; f < 4; ++f) {
      const int ra  = (wr * 64 + f * 16 + rr) * 32 + co;
      const int rb2 = (wc * 64 + f * 16 + rr) * 32 + co;
      ah[f]  = *(const bf16x8*)&lds[0][ra];
      al[f]  = *(const bf16x8*)&lds[1][ra];
      bh_[f] = *(const bf16x8*)&lds[2][rb2];
      bl_[f] = *(const bf16x8*)&lds[3][rb2];
    }
#pragma unroll
    for (int m = 0; m < 4; ++m)
#pragma unroll
      for (int n = 0; n < 4; ++n) {
        acc[m][n] = __builtin_amdgcn_mfma_f32_16x16x32_bf16(ah[m], bh_[n], acc[m][n], 0, 0, 0);
        acc[m][n] = __builtin_amdgcn_mfma_f32_16x16x32_bf16(ah[m], bl_[n], acc[m][n], 0, 0, 0);
        acc[m][n] = __builtin_amdgcn_mfma_f32_16x16x32_bf16(al[m], bh_[n], acc[m][n], 0, 0, 0);
      }
  }

  const int cn0 = lane & 15;
  const int rm0 = (lane >> 4) * 4;
#pragma unroll
  for (int n = 0; n < 4; ++n) {
    const int ng = bn * 128 + wc * 64 + n * 16 + cn0;
    const float bv = bias[ng];
#pragma unroll
    for (int m = 0; m < 4; ++m) {
      const int mg = bm * 128 + wr * 64 + m * 16 + rm0;
#pragma unroll
      for (int r = 0; r < 4; ++r) {
        const float v = acc[m][n][r] + bv;
        const u16 hb = f2bf(v);
        const u16 lb = f2bf(v - bf2f(hb));
        Cp[(size_t)(mg + r) * 512 + ng] = (uint32_t)hb | ((uint32_t)lb << 16);
      }
    }
  }
}

// ---------------------------------------------------------------------------
// gemm_packA: A PACKED u32 (hi|lo<<16); B hi/lo u16 planes; C = f32 out.
// ---------------------------------------------------------------------------
__global__ __launch_bounds__(256) void gemm_packA(
    const uint32_t* __restrict__ A, const u16* __restrict__ Bh,
    const u16* __restrict__ Bl, const float* __restrict__ bias,
    float* __restrict__ C)
{
  __shared__ uint32_t ldsA[128 * 32];              // 16 KB
  __shared__ u16 ldsBh[128 * 32], ldsBl[128 * 32]; // 8 + 8 KB
  const int tid = threadIdx.x;
  const int lane = tid & 63;
  const int w = tid >> 6;
  const int vid = (blockIdx.x & 7) * 256 + (blockIdx.x >> 3);  // XCD swizzle
  const int bn = vid & 3;
  const int bm = vid >> 2;
  const int wr = w >> 1, wcq = w & 1;

  f32x4 acc[4][4];
#pragma unroll
  for (int m = 0; m < 4; ++m)
#pragma unroll
    for (int n = 0; n < 4; ++n) acc[m][n] = (f32x4){0.f, 0.f, 0.f, 0.f};

  for (int kt = 0; kt < 16; ++kt) {
    const int k0 = kt * 32;
    __syncthreads();
#pragma unroll
    for (int i = 0; i < 4; ++i) {
      const int rb8 = i * 4 + w;
      const int row = rb8 * 8 + (lane >> 3);
      const uint32_t* src =
          A + (size_t)(bm * 128 + row) * 512 + k0 + (lane & 7) * 4;
      gload_lds16(src, &ldsA[rb8 * 8 * 32]);
    }
#pragma unroll
    for (int i = 0; i < 2; ++i) {
      const int rb16 = i * 4 + w;
      const int row = rb16 * 16 + (lane >> 2);
      const int sc = (lane & 3) * 8;
      gload_lds16(Bh + (size_t)(bn * 128 + row) * 512 + k0 + sc,
                  &ldsBh[rb16 * 16 * 32]);
      gload_lds16(Bl + (size_t)(bn * 128 + row) * 512 + k0 + sc,
                  &ldsBl[rb16 * 16 * 32]);
    }
    __syncthreads();

    bf16x8 ah[4], al[4], bh_[4], bl_[4];
    const int co = (lane >> 4) * 8;
    const int rr = lane & 15;
#pragma unroll
    for (int f = 0; f < 4; ++f) {
      const int ra = (wr * 64 + f * 16 + rr) * 32 + co;
      const uint4 p0 = *(const uint4*)&ldsA[ra];
      const uint4 p1 = *(const uint4*)&ldsA[ra + 4];
      BF8 hv, lv;
      uint32_t* hd = (uint32_t*)&hv.q4;
      uint32_t* ld = (uint32_t*)&lv.q4;
      hd[0] = __builtin_amdgcn_perm(p0.y, p0.x, 0x05040100u);
      hd[1] = __builtin_amdgcn_perm(p0.w, p0.z, 0x05040100u);
      hd[2] = __builtin_amdgcn_perm(p1.y, p1.x, 0x05040100u);
      hd[3] = __builtin_amdgcn_perm(p1.w, p1.z, 0x05040100u);
      ld[0] = __builtin_amdgcn_perm(p0.y, p0.x, 0x07060302u);
      ld[1] = __builtin_amdgcn_perm(p0.w, p0.z, 0x07060302u);
      ld[2] = __builtin_amdgcn_perm(p1.y, p1.x, 0x07060302u);
      ld[3] = __builtin_amdgcn_perm(p1.w, p1.z, 0x07060302u);
      ah[f] = hv.v; al[f] = lv.v;
      const int rb2 = (wcq * 64 + f * 16 + rr) * 32 + co;
      bh_[f] = *(const bf16x8*)&ldsBh[rb2];
      bl_[f] = *(const bf16x8*)&ldsBl[rb2];
    }
#pragma unroll
    for (int m = 0; m < 4; ++m)
#pragma unroll
      for (int n = 0; n < 4; ++n) {
        acc[m][n] = __builtin_amdgcn_mfma_f32_16x16x32_bf16(ah[m], bh_[n], acc[m][n], 0, 0, 0);
        acc[m][n] = __builtin_amdgcn_mfma_f32_16x16x32_bf16(ah[m], bl_[n], acc[m][n], 0, 0, 0);
        acc[m][n] = __builtin_amdgcn_mfma_f32_16x16x32_bf16(al[m], bh_[n], acc[m][n], 0, 0, 0);
      }
  }

  const int cn0 = lane & 15;
  const int rm0 = (lane >> 4) * 4;
#pragma unroll
  for (int n = 0; n < 4; ++n) {
    const int ng = bn * 128 + wcq * 64 + n * 16 + cn0;
    const float bv = bias[ng];
#pragma unroll
    for (int m = 0; m < 4; ++m) {
      const int mg = bm * 128 + wr * 64 + m * 16 + rm0;
#pragma unroll
      for (int r = 0; r < 4; ++r)
        C[(size_t)(mg + r) * 512 + ng] = acc[m][n][r] + bv;
    }
  }
}

// ---------------------------------------------------------------------------
// K2: MFMA routing; xp read PACKED (A-frags via v_perm). Per-wave LDS
// transpose -> coalesced packed u32 stores. wbuf is strictly per-wave, so
// the tm loop has NO block barriers (intra-wave lgkmcnt orders wbuf).
// ---------------------------------------------------------------------------
__global__ __launch_bounds__(256, 4) void k2_route(
    const uint32_t* __restrict__ xpq, const float* __restrict__ Wsl,
    const float* __restrict__ bsl, const float* __restrict__ Wt1,
    const float* __restrict__ bt1, const float* __restrict__ Wt2,
    const float* __restrict__ bt2, const float* __restrict__ tbias,
    uint32_t* __restrict__ wcp)
{
  __shared__ u16 Wf[2][8][2][64][8];      // frag-ordered W planes, 32 KB
  __shared__ uint32_t wbuf[4][16][68];    // per-wave transpose, hi|lo<<16

  const int tid = threadIdx.x;
  const int l = tid & 63, wid = tid >> 6;
  const int l15 = l & 15, q = l >> 4;
  const int h = blockIdx.x >> 8;
  const int chunk = blockIdx.x & 255;

  // ---- stage W fragments (once per block) ----
#pragma unroll
  for (int it = 0; it < 8; ++it) {
    const int slot = tid + it * 256;
    const int p = slot >> 10;
    const int rest = slot & 1023;
    const int nn = rest >> 7;
    const int kk = (rest >> 6) & 1;
    const int sl = rest & 63;
    const int row = nn * 16 + (sl & 15);
    const int kb = kk * 32 + (sl >> 4) * 8;
    const float* src = (row < 64) ? (Wsl + row * 64 + kb)
                                  : (Wt1 + (row - 64) * 64 + kb);
#pragma unroll
    for (int e = 0; e < 8; ++e) {
      const float v = src[e];
      const u16 hb = f2bf(v);
      Wf[p][nn][kk][sl][e] = (p == 0) ? hb : f2bf(v - bf2f(hb));
    }
  }
  __syncthreads();

  float bslv[4], bt1v[4], wt2v[4];
#pragma unroll
  for (int j = 0; j < 4; ++j) {
    bslv[j] = bsl[j * 16 + l15];
    bt1v[j] = bt1[j * 16 + l15];
    wt2v[j] = Wt2[j * 16 + l15];
  }
  const float bt2v = bt2[0], tbv = tbias[h];

#pragma unroll 1
  for (int tm = 0; tm < 4; ++tm) {
    const int n0t = chunk * 256 + (tm >> 1) * 128 + wid * 32 + (tm & 1) * 16;

    // ---- A fragments from packed xp via v_perm ----
    bf16x8 ah[2], al[2];
#pragma unroll
    for (int kk = 0; kk < 2; ++kk) {
      const uint32_t* sp = xpq + (size_t)(n0t + l15) * 512 + h * 64
                           + kk * 32 + q * 8;
      const uint4 p0 = *(const uint4*)sp;
      const uint4 p1 = *(const uint4*)(sp + 4);
      BF8 hv, lv;
      uint32_t* hd = (uint32_t*)&hv.q4;
      uint32_t* ld = (uint32_t*)&lv.q4;
      hd[0] = __builtin_amdgcn_perm(p0.y, p0.x, 0x05040100u);
      hd[1] = __builtin_amdgcn_perm(p0.w, p0.z, 0x05040100u);
      hd[2] = __builtin_amdgcn_perm(p1.y, p1.x, 0x05040100u);
      hd[3] = __builtin_amdgcn_perm(p1.w, p1.z, 0x05040100u);
      ld[0] = __builtin_amdgcn_perm(p0.y, p0.x, 0x07060302u);
      ld[1] = __builtin_amdgcn_perm(p0.w, p0.z, 0x07060302u);
      ld[2] = __builtin_amdgcn_perm(p1.y, p1.x, 0x07060302u);
      ld[3] = __builtin_amdgcn_perm(p1.w, p1.z, 0x07060302u);
      ah[kk] = hv.v; al[kk] = lv.v;
    }

    // ---- MFMA: [16 tok] x [128 cols], K=64, 3-term ----
    f32x4 acc[8];
#pragma unroll
    for (int n = 0; n < 8; ++n) acc[n] = (f32x4){0.f, 0.f, 0.f, 0.f};
#pragma unroll
    for (int kk = 0; kk < 2; ++kk)
#pragma unroll
      for (int nn = 0; nn < 8; ++nn) {
        BF8 whf, wlf;
        whf.q4 = *(const uint4*)&Wf[0][nn][kk][l][0];
        wlf.q4 = *(const uint4*)&Wf[1][nn][kk][l][0];
        acc[nn] = __builtin_amdgcn_mfma_f32_16x16x32_bf16(ah[kk], whf.v, acc[nn], 0, 0, 0);
        acc[nn] = __builtin_amdgcn_mfma_f32_16x16x32_bf16(ah[kk], wlf.v, acc[nn], 0, 0, 0);
        acc[nn] = __builtin_amdgcn_mfma_f32_16x16x32_bf16(al[kk], whf.v, acc[nn], 0, 0, 0);
      }

    // ---- temperature per r ----
    float itv[4];
#pragma unroll
    for (int r = 0; r < 4; ++r) {
      float part = 0.f;
#pragma unroll
      for (int j = 0; j < 4; ++j)
        part += gelu_fast(acc[4 + j][r] + bt1v[j]) * wt2v[j];
      part += __shfl_xor(part, 1);
      part += __shfl_xor(part, 2);
      part += __shfl_xor(part, 4);
      part += __shfl_xor(part, 8);
      const float tval = gelu_fast(part + bt2v) + tbv;
      itv[r] = 1.0f / fmaxf(tval, 0.01f);
    }

    // ---- logits: bias + threefry-gumbel + /t ----
    const uint32_t pbase = ((uint32_t)((h << 16) | (n0t + q * 4))) << 6;
#pragma unroll
    for (int j = 0; j < 4; ++j) {
      const uint32_t cc = j * 16 + l15;
#pragma unroll
      for (int r = 0; r < 4; ++r) {
        const uint32_t bits = threefry_bits(pbase + ((uint32_t)r << 6) + cc);
        const float u = __uint_as_float((bits >> 9) | 0x3f800000u) - 1.0f;
        const float gin = -__logf(u + 1e-8f);
        const float gn = -__logf(gin + 1e-8f);
        acc[j][r] = (acc[j][r] + bslv[j] + gn) * itv[r];
      }
    }

    // ---- softmax over cols ----
#pragma unroll
    for (int r = 0; r < 4; ++r) {
      float mx = fmaxf(fmaxf(acc[0][r], acc[1][r]),
                       fmaxf(acc[2][r], acc[3][r]));
      mx = fmaxf(mx, __shfl_xor(mx, 1));
      mx = fmaxf(mx, __shfl_xor(mx, 2));
      mx = fmaxf(mx, __shfl_xor(mx, 4));
      mx = fmaxf(mx, __shfl_xor(mx, 8));
      float se = 0.f;
#pragma unroll
      for (int j = 0; j < 4; ++j) {
        const float e = __expf(acc[j][r] - mx);
        acc[j][r] = e;
        se += e;
      }
      se += __shfl_xor(se, 1);
      se += __shfl_xor(se, 2);
      se += __shfl_xor(se, 4);
      se += __shfl_xor(se, 8);
      const float inv = 1.0f / se;
#pragma unroll
      for (int j = 0; j < 4; ++j) acc[j][r] *= inv;
    }

    // ---- pack hi|lo into per-wave LDS transpose (wave-private; no barrier)
#pragma unroll
    for (int j = 0; j < 4; ++j)
#pragma unroll
      for (int r = 0; r < 4; ++r) {
        const float wv = acc[j][r];
        const u16 hb = f2bf(wv);
        const u16 lb = f2bf(wv - bf2f(hb));
        wbuf[wid][q * 4 + r][j * 16 + l15] = (uint32_t)hb | ((uint32_t)lb << 16);
      }

    // ---- coalesced packed stores: 16 tok x 16 uint4 -> 64 lanes x 4 ----
#pragma unroll
    for (int it = 0; it < 4; ++it) {
      const int t = l >> 2;
      const int qq = (l & 3) + it * 4;    // 0..15
      const uint4 v = *(const uint4*)&wbuf[wid][t][qq * 4];
      *(uint4*)(wcp + (size_t)(n0t + t) * 512 + h * 64 + qq * 4) = v;
    }
  }
}

// ---------------------------------------------------------------------------
// K3: MFMA pooling. Per head: tok_num[g,d] = sum_n w[n,g]*x[n,d] (K=65536).
// Grid = 8 heads x 64 chunks (1024 tok); 4 waves x 256 tok; per wave 8 tiles
// of 32 tokens. Fragment gathers straight from global. 3-term split-bf16.
// ---------------------------------------------------------------------------
__global__ __launch_bounds__(256, 2) void k3_pool(
    const uint32_t* __restrict__ xpq, const uint32_t* __restrict__ wcp,
    float* __restrict__ tok_num, float* __restrict__ nrm)
{
  __shared__ float red[64][65];
  const int h = blockIdx.x >> 6;
  const int chunk = blockIdx.x & 63;
  const int lane = threadIdx.x & 63;
  const int wid = threadIdx.x >> 6;
  const int l15 = lane & 15, q = lane >> 4;

  f32x4 acc[4][4];
#pragma unroll
  for (int m = 0; m < 4; ++m)
#pragma unroll
    for (int n = 0; n < 4; ++n) acc[m][n] = (f32x4){0.f, 0.f, 0.f, 0.f};
  float csum[4] = {0.f, 0.f, 0.f, 0.f};

  const int tw = chunk * 1024 + wid * 256;
#pragma unroll 1
  for (int tt = 0; tt < 8; ++tt) {
    const int t0 = tw + tt * 32;
    uint32_t wreg[4][8], xreg[4][8];
#pragma unroll
    for (int e = 0; e < 8; ++e) {
      const size_t rb = (size_t)(t0 + q * 8 + e) * 512 + h * 64 + l15;
#pragma unroll
      for (int m = 0; m < 4; ++m) {
        wreg[m][e] = wcp[rb + m * 16];
        xreg[m][e] = xpq[rb + m * 16];
      }
    }
    bf16x8 whf[4], wlf[4], xhf[4], xlf[4];
#pragma unroll
    for (int m = 0; m < 4; ++m) {
      BF8 hv, lv, xh, xl;
      uint32_t* hd = (uint32_t*)&hv.q4;
      uint32_t* ld = (uint32_t*)&lv.q4;
      uint32_t* xhd = (uint32_t*)&xh.q4;
      uint32_t* xld = (uint32_t*)&xl.q4;
#pragma unroll
      for (int p = 0; p < 4; ++p) {
        hd[p]  = __builtin_amdgcn_perm(wreg[m][2*p+1], wreg[m][2*p], 0x05040100u);
        ld[p]  = __builtin_amdgcn_perm(wreg[m][2*p+1], wreg[m][2*p], 0x07060302u);
        xhd[p] = __builtin_amdgcn_perm(xreg[m][2*p+1], xreg[m][2*p], 0x05040100u);
        xld[p] = __builtin_amdgcn_perm(xreg[m][2*p+1], xreg[m][2*p], 0x07060302u);
      }
      whf[m] = hv.v; wlf[m] = lv.v; xhf[m] = xh.v; xlf[m] = xl.v;
#pragma unroll
      for (int e = 0; e < 8; ++e)
        csum[m] += __uint_as_float(wreg[m][e] << 16)
                 + __uint_as_float(wreg[m][e] & 0xffff0000u);
    }
#pragma unroll
    for (int m = 0; m < 4; ++m)
#pragma unroll
      for (int n = 0; n < 4; ++n) {
        acc[m][n] = __builtin_amdgcn_mfma_f32_16x16x32_bf16(whf[m], xhf[n], acc[m][n], 0, 0, 0);
        acc[m][n] = __builtin_amdgcn_mfma_f32_16x16x32_bf16(whf[m], xlf[n], acc[m][n], 0, 0, 0);
        acc[m][n] = __builtin_amdgcn_mfma_f32_16x16x32_bf16(wlf[m], xhf[n], acc[m][n], 0, 0, 0);
      }
  }

  // nrm: reduce csum over q-groups, lanes q==0 add 4 g-values each
#pragma unroll
  for (int m = 0; m < 4; ++m) {
    csum[m] += __shfl_xor(csum[m], 16);
    csum[m] += __shfl_xor(csum[m], 32);
  }
  if (q == 0) {
#pragma unroll
    for (int m = 0; m < 4; ++m)
      atomicAdd(&nrm[h * 64 + m * 16 + l15], csum[m]);
  }

  // cross-wave reduce
  for (int w = 0; w < 4; ++w) {
    if (wid == w) {
#pragma unroll
      for (int m = 0; m < 4; ++m)
#pragma unroll
        for (int n = 0; n < 4; ++n)
#pragma unroll
          for (int r = 0; r < 4; ++r) {
            const int g = m * 16 + q * 4 + r;
            const int d = n * 16 + l15;
            if (w == 0) red[g][d] = acc[m][n][r];
            else        red[g][d] += acc[m][n][r];
          }
    }
    __syncthreads();
  }
  for (int e = threadIdx.x; e < 4096; e += 256)
    atomicAdd(&tok_num[h * 4096 + e], red[e >> 6][e & 63]);
}

// ---------------------------------------------------------------------------
// K4a: per-head attention over G=64 slice tokens. One block per head.
// ---------------------------------------------------------------------------
__global__ __launch_bounds__(256) void k4_attn(
    const float* __restrict__ tok_num, const float* __restrict__ nrm,
    const float* __restrict__ Wq, const float* __restrict__ Wk,
    const float* __restrict__ Wv, const float* __restrict__ Wo,
    float* __restrict__ o_out)
{
  __shared__ float T[64][65], Abuf[64][65], Bbuf[64][65], Wbuf[64][65], S2[64][65];
  const int h = blockIdx.x;
  const int tid = threadIdx.x;

  for (int e = tid; e < 4096; e += 256) {
    const int g = e >> 6, d = e & 63;
    T[g][d] = tok_num[h * 4096 + e] / (nrm[h * 64 + g] + 1e-5f);
  }
  for (int e = tid; e < 4096; e += 256) Wbuf[e >> 6][e & 63] = Wq[e];
  __syncthreads();

  const int g = tid >> 2, d0 = (tid & 3) * 16;
  float r[16];

#pragma unroll
  for (int j = 0; j < 16; ++j) r[j] = 0.f;
  for (int e = 0; e < 64; ++e) {
    const float tv = T[g][e];
#pragma unroll
    for (int j = 0; j < 16; ++j) r[j] = fmaf(tv, Wbuf[d0 + j][e], r[j]);
  }
#pragma unroll
  for (int j = 0; j < 16; ++j) Abuf[g][d0 + j] = r[j];
  __syncthreads();

  for (int e = tid; e < 4096; e += 256) Wbuf[e >> 6][e & 63] = Wk[e];
  __syncthreads();

#pragma unroll
  for (int j = 0; j < 16; ++j) r[j] = 0.f;
  for (int e = 0; e < 64; ++e) {
    const float tv = T[g][e];
#pragma unroll
    for (int j = 0; j < 16; ++j) r[j] = fmaf(tv, Wbuf[d0 + j][e], r[j]);
  }
#pragma unroll
  for (int j = 0; j < 16; ++j) Bbuf[g][d0 + j] = r[j];
  __syncthreads();

#pragma unroll
  for (int j = 0; j < 16; ++j) r[j] = 0.f;
  for (int e = 0; e < 64; ++e) {
    const float qv = Abuf[g][e] * 0.125f;
#pragma unroll
    for (int j = 0; j < 16; ++j) r[j] = fmaf(qv, Bbuf[d0 + j][e], r[j]);
  }
#pragma unroll
  for (int j = 0; j < 16; ++j) S2[g][d0 + j] = r[j];
  __syncthreads();

  if (tid < 64) {
    float mx = -1e30f;
    for (int j = 0; j < 64; ++j) mx = fmaxf(mx, S2[tid][j]);
    float sum = 0.f;
    for (int j = 0; j < 64; ++j) {
      const float e2 = expf(S2[tid][j] - mx);
      S2[tid][j] = e2;
      sum += e2;
    }
    const float inv = 1.0f / sum;
    for (int j = 0; j < 64; ++j) S2[tid][j] *= inv;
  }
  __syncthreads();

  for (int e = tid; e < 4096; e += 256) Wbuf[e >> 6][e & 63] = Wv[e];
  __syncthreads();

#pragma unroll
  for (int j = 0; j < 16; ++j) r[j] = 0.f;
  for (int e = 0; e < 64; ++e) {
    const float tv = T[g][e];
#pragma unroll
    for (int j = 0; j < 16; ++j) r[j] = fmaf(tv, Wbuf[d0 + j][e], r[j]);
  }
  __syncthreads();
#pragma unroll
  for (int j = 0; j < 16; ++j) Bbuf[g][d0 + j] = r[j];
  __syncthreads();

#pragma unroll
  for (int j = 0; j < 16; ++j) r[j] = 0.f;
  for (int e = 0; e < 64; ++e) {
    const float sv = S2[g][e];
#pragma unroll
    for (int j = 0; j < 16; ++j) r[j] = fmaf(sv, Bbuf[e][d0 + j], r[j]);
  }
  __syncthreads();
#pragma unroll
  for (int j = 0; j < 16; ++j) Abuf[g][d0 + j] = r[j];
  for (int e = tid; e < 4096; e += 256) Wbuf[e >> 6][e & 63] = Wo[e];
  __syncthreads();

#pragma unroll
  for (int j = 0; j < 16; ++j) r[j] = 0.f;
  for (int e = 0; e < 64; ++e) {
    const float ov = Abuf[g][e];
#pragma unroll
    for (int j = 0; j < 16; ++j) r[j] = fmaf(ov, Wbuf[d0 + j][e], r[j]);
  }
#pragma unroll
  for (int j = 0; j < 16; ++j) o_out[h * 4096 + g * 64 + d0 + j] = r[j];
}

// ---------------------------------------------------------------------------
// K4b: M2T[j][hg] = sum_d o[hg][d] * W_out[j][h*64+d]  -> hi/lo bf16 planes
// ---------------------------------------------------------------------------
__global__ __launch_bounds__(256) void k4b_m2(
    const float* __restrict__ o, const float* __restrict__ Wout,
    u16* __restrict__ M2h, u16* __restrict__ M2l)
{
  const int j = blockIdx.x >> 1;
  const int hg = ((blockIdx.x & 1) << 8) + threadIdx.x;
  const int h = hg >> 6;
  const float* orow = &o[hg * 64];
  const float* wrow = &Wout[j * 512 + h * 64];
  float s = 0.f;
#pragma unroll
  for (int d = 0; d < 64; ++d) s = fmaf(orow[d], wrow[d], s);
  const u16 hb = f2bf(s);
  M2h[j * 512 + hg] = hb;
  M2l[j * 512 + hg] = f2bf(s - bf2f(hb));
}

// ---------------------------------------------------------------------------
extern "C" void kernel_launch(void* const* d_in, const int* in_sizes, int n_in,
                              void* d_out, int out_size, void* d_ws, size_t ws_size,
                              hipStream_t stream)
{
  const float* x      = (const float*)d_in[0];
  const float* W_x    = (const float*)d_in[1];
  const float* b_x    = (const float*)d_in[2];
  const float* W_sl   = (const float*)d_in[3];
  const float* b_sl   = (const float*)d_in[4];
  const float* W_t1   = (const float*)d_in[5];
  const float* b_t1   = (const float*)d_in[6];
  const float* W_t2   = (const float*)d_in[7];
  const float* b_t2   = (const float*)d_in[8];
  const float* t_bias = (const float*)d_in[9];
  const float* Wq     = (const float*)d_in[10];
  const float* Wk     = (const float*)d_in[11];
  const float* Wv     = (const float*)d_in[12];
  const float* Wo     = (const float*)d_in[13];
  const float* W_out  = (const float*)d_in[14];
  const float* b_out  = (const float*)d_in[15];

  float* out = (float*)d_out;
  uint32_t* xpq = (uint32_t*)d_out;  // packed xp lives in d_out until GEMM2

  char* ws = (char*)d_ws;
  u16*      Ahi   = (u16*)(ws);                  // x hi plane (GEMM1)
  u16*      Alo   = (u16*)(ws + 67108864);       // x lo plane (GEMM1)
  uint32_t* wcp   = (uint32_t*)(ws);             // packed wcat (after GEMM1)
  u16*      Bhi   = (u16*)(ws + 134217728);      // Wx hi, then M2T hi
  u16*      Blo   = (u16*)(ws + 134742016);      // Wx lo, then M2T lo
  float* tok_num  = (float*)(ws + 135266304);    // 131072 B
  float* nrm      = (float*)(ws + 135397376);    // 2048 B
  float* o_buf    = (float*)(ws + 135399424);    // 131072 B

  conv_split<<<2048, 256, 0, stream>>>(x, Ahi, Alo, 8388608);
  conv_split<<<256, 256, 0, stream>>>(W_x, Bhi, Blo, 65536);
  gemm_split<<<2048, 256, 0, stream>>>(Ahi, Alo, Bhi, Blo, b_x, xpq);

  hipMemsetAsync(tok_num, 0, 133120, stream);  // tok_num + nrm (contiguous)

  k2_route<<<2048, 256, 0, stream>>>(xpq, W_sl, b_sl, W_t1, b_t1, W_t2, b_t2,
                                     t_bias, wcp);
  k3_pool<<<512, 256, 0, stream>>>(xpq, wcp, tok_num, nrm);
  k4_attn<<<8, 256, 0, stream>>>(tok_num, nrm, Wq, Wk, Wv, Wo, o_buf);
  k4b_m2<<<1024, 256, 0, stream>>>(o_buf, W_out, Bhi, Blo);    // overwrites Wx-split
  gemm_packA<<<2048, 256, 0, stream>>>(wcp, Bhi, Blo, b_out, out);
}

// Round 17
// 552.907 us; speedup vs baseline: 1.0985x; 1.0532x over previous
//
#include <hip/hip_runtime.h>
#include <stdint.h>

typedef unsigned short u16;
typedef __bf16 bf16x8 __attribute__((ext_vector_type(8)));
typedef float f32x4 __attribute__((ext_vector_type(4)));

// ---------------------------------------------------------------------------
// EideticPhysicsAttention: N=65536 tokens, HID=512, H=8 heads, D=64, G=64.
//   conv  : split f32 -> (hi,lo) bf16 planes for x and W_x
//   K1    gemm_split : xp = x @ W_x.T + b_x  -> PACKED u32 (hi|lo<<16) in d_out
//   K2    k2_route   : MFMA logits+t1, threefry-gumbel, softmax -> wcat
//                      packed u32 (per-wave wbuf; barriers per m-block act as
//                      live-range scissors: VGPR 68 vs 120 without, +25us)
//   K3    k3_pool    : MFMA pooling: tok_num[h,g,d] = sum_n w*x ; nrm
//   K4a   k4_attn    : per-head 64-token attention -> o[h,g,d]
//   K4b   k4b_m2     : M2T[j][hg] hi/lo = sum_d o[hg][d]*W_out[j][h*64+d]
//   K5    gemm_packA : out = wcat @ M2T.T + b_out      (overwrites d_out)
// ---------------------------------------------------------------------------

__device__ __forceinline__ u16 f2bf(float f) {   // RNE bf16
  uint32_t u = __float_as_uint(f);
  uint32_t r = u + 0x7fffu + ((u >> 16) & 1u);
  return (u16)(r >> 16);
}
__device__ __forceinline__ float bf2f(u16 h) {
  return __uint_as_float(((uint32_t)h) << 16);
}

union BF8 { bf16x8 v; u16 u[8]; uint4 q4; };

__device__ __forceinline__ float gelu_fast(float x) {
  const float c = 0.79788456080286535588f;
  float z = c * fmaf(0.044715f, x * x * x, x);
  return x / (1.0f + __expf(-2.0f * z));
}

__device__ __forceinline__ uint32_t rotl32(uint32_t v, int s) {
  return (v << s) | (v >> (32 - s));
}

// JAX threefry2x32, key=(0,1) from jax.random.key(1), partitionable path.
__device__ __forceinline__ uint32_t threefry_bits(uint32_t idx) {
  const uint32_t k0 = 0u, k1 = 1u;
  const uint32_t k2 = 0x1BD11BDAu ^ k0 ^ k1;
  uint32_t x0 = 0u + k0;
  uint32_t x1 = idx + k1;
#define TF_R(r) { x0 += x1; x1 = rotl32(x1, r); x1 ^= x0; }
  TF_R(13) TF_R(15) TF_R(26) TF_R(6)
  x0 += k1; x1 += k2 + 1u;
  TF_R(17) TF_R(29) TF_R(16) TF_R(24)
  x0 += k2; x1 += k0 + 2u;
  TF_R(13) TF_R(15) TF_R(26) TF_R(6)
  x0 += k0; x1 += k1 + 3u;
  TF_R(17) TF_R(29) TF_R(16) TF_R(24)
  x0 += k1; x1 += k2 + 4u;
  TF_R(13) TF_R(15) TF_R(26) TF_R(6)
  x0 += k2; x1 += k0 + 5u;
#undef TF_R
  return x0 ^ x1;
}

__device__ __forceinline__ void gload_lds16(const void* g, void* l) {
  __builtin_amdgcn_global_load_lds(
      (const __attribute__((address_space(1))) void*)g,
      (__attribute__((address_space(3))) void*)l, 16, 0, 0);
}

// ---------------------------------------------------------------------------
// conv_split: f32 -> hi/lo bf16 planes (grid-stride over float4 quads)
// ---------------------------------------------------------------------------
__global__ __launch_bounds__(256) void conv_split(
    const float* __restrict__ in, u16* __restrict__ hi, u16* __restrict__ lo,
    int nq)
{
  for (int i = blockIdx.x * 256 + threadIdx.x; i < nq; i += gridDim.x * 256) {
    float4 v = ((const float4*)in)[i];
    ushort4 h, l;
    h.x = f2bf(v.x); l.x = f2bf(v.x - bf2f(h.x));
    h.y = f2bf(v.y); l.y = f2bf(v.y - bf2f(h.y));
    h.z = f2bf(v.z); l.z = f2bf(v.z - bf2f(h.z));
    h.w = f2bf(v.w); l.w = f2bf(v.w - bf2f(h.w));
    ((ushort4*)hi)[i] = h;
    ((ushort4*)lo)[i] = l;
  }
}

// ---------------------------------------------------------------------------
// gemm_split: Cp[m][j] = pack( sum_k (Ah+Al)[m][k]*(Bh+Bl)[j][k] + bias[j] )
// Output PACKED u32 (hi | lo<<16).  128x128 tile, BK=32, XCD swizzle.
// ---------------------------------------------------------------------------
__global__ __launch_bounds__(256) void gemm_split(
    const u16* __restrict__ Ah, const u16* __restrict__ Al,
    const u16* __restrict__ Bh, const u16* __restrict__ Bl,
    const float* __restrict__ bias, uint32_t* __restrict__ Cp)
{
  __shared__ u16 lds[4][4096];   // [Ah,Al,Bh,Bl][128 rows * 32 k] = 32 KB
  const int tid = threadIdx.x;
  const int lane = tid & 63;
  const int w = tid >> 6;
  const int vid = (blockIdx.x & 7) * 256 + (blockIdx.x >> 3);  // XCD swizzle
  const int bn = vid & 3;
  const int bm = vid >> 2;
  const int wr = w >> 1, wc = w & 1;

  f32x4 acc[4][4];
#pragma unroll
  for (int m = 0; m < 4; ++m)
#pragma unroll
    for (int n = 0; n < 4; ++n) acc[m][n] = (f32x4){0.f, 0.f, 0.f, 0.f};

  const int srow = lane >> 2;
  const int scol = (lane & 3) * 8;

  for (int kt = 0; kt < 16; ++kt) {
    const int k0 = kt * 32;
    __syncthreads();
#pragma unroll
    for (int i = 0; i < 8; ++i) {
      const int mat = i & 3;
      const int rb = w * 2 + (i >> 2);
      const int row = rb * 16 + srow;
      const u16* base = (mat == 0) ? Ah : (mat == 1) ? Al
                       : (mat == 2) ? Bh : Bl;
      const int tbase = (mat < 2) ? bm * 128 : bn * 128;
      const u16* src = base + (size_t)(tbase + row) * 512 + k0 + scol;
      gload_lds16(src, &lds[mat][rb * 512]);
    }
    __syncthreads();

    bf16x8 ah[4], al[4], bh_[4], bl_[4];
    const int co = (lane >> 4) * 8;
    const int rr = lane & 15;
#pragma unroll
    for (int f = 0; f < 4; ++f) {
      const int ra  = (wr * 64 + f * 16 + rr) * 32 + co;
      const int rb2 = (wc * 64 + f * 16 + rr) * 32 + co;
      ah[f]  = *(const bf16x8*)&lds[0][ra];
      al[f]  = *(const bf16x8*)&lds[1][ra];
      bh_[f] = *(const bf16x8*)&lds[2][rb2];
      bl_[f] = *(const bf16x8*)&lds[3][rb2];
    }
#pragma unroll
    for (int m = 0; m < 4; ++m)
#pragma unroll
      for (int n = 0; n < 4; ++n) {
        acc[m][n] = __builtin_amdgcn_mfma_f32_16x16x32_bf16(ah[m], bh_[n], acc[m][n], 0, 0, 0);
        acc[m][n] = __builtin_amdgcn_mfma_f32_16x16x32_bf16(ah[m], bl_[n], acc[m][n], 0, 0, 0);
        acc[m][n] = __builtin_amdgcn_mfma_f32_16x16x32_bf16(al[m], bh_[n], acc[m][n], 0, 0, 0);
      }
  }

  const int cn0 = lane & 15;
  const int rm0 = (lane >> 4) * 4;
#pragma unroll
  for (int n = 0; n < 4; ++n) {
    const int ng = bn * 128 + wc * 64 + n * 16 + cn0;
    const float bv = bias[ng];
#pragma unroll
    for (int m = 0; m < 4; ++m) {
      const int mg = bm * 128 + wr * 64 + m * 16 + rm0;
#pragma unroll
      for (int r = 0; r < 4; ++r) {
        const float v = acc[m][n][r] + bv;
        const u16 hb = f2bf(v);
        const u16 lb = f2bf(v - bf2f(hb));
        Cp[(size_t)(mg + r) * 512 + ng] = (uint32_t)hb | ((uint32_t)lb << 16);
      }
    }
  }
}

// ---------------------------------------------------------------------------
// gemm_packA: A PACKED u32 (hi|lo<<16); B hi/lo u16 planes; C = f32 out.
// ---------------------------------------------------------------------------
__global__ __launch_bounds__(256) void gemm_packA(
    const uint32_t* __restrict__ A, const u16* __restrict__ Bh,
    const u16* __restrict__ Bl, const float* __restrict__ bias,
    float* __restrict__ C)
{
  __shared__ uint32_t ldsA[128 * 32];              // 16 KB
  __shared__ u16 ldsBh[128 * 32], ldsBl[128 * 32]; // 8 + 8 KB
  const int tid = threadIdx.x;
  const int lane = tid & 63;
  const int w = tid >> 6;
  const int vid = (blockIdx.x & 7) * 256 + (blockIdx.x >> 3);  // XCD swizzle
  const int bn = vid & 3;
  const int bm = vid >> 2;
  const int wr = w >> 1, wcq = w & 1;

  f32x4 acc[4][4];
#pragma unroll
  for (int m = 0; m < 4; ++m)
#pragma unroll
    for (int n = 0; n < 4; ++n) acc[m][n] = (f32x4){0.f, 0.f, 0.f, 0.f};

  for (int kt = 0; kt < 16; ++kt) {
    const int k0 = kt * 32;
    __syncthreads();
#pragma unroll
    for (int i = 0; i < 4; ++i) {
      const int rb8 = i * 4 + w;
      const int row = rb8 * 8 + (lane >> 3);
      const uint32_t* src =
          A + (size_t)(bm * 128 + row) * 512 + k0 + (lane & 7) * 4;
      gload_lds16(src, &ldsA[rb8 * 8 * 32]);
    }
#pragma unroll
    for (int i = 0; i < 2; ++i) {
      const int rb16 = i * 4 + w;
      const int row = rb16 * 16 + (lane >> 2);
      const int sc = (lane & 3) * 8;
      gload_lds16(Bh + (size_t)(bn * 128 + row) * 512 + k0 + sc,
                  &ldsBh[rb16 * 16 * 32]);
      gload_lds16(Bl + (size_t)(bn * 128 + row) * 512 + k0 + sc,
                  &ldsBl[rb16 * 16 * 32]);
    }
    __syncthreads();

    bf16x8 ah[4], al[4], bh_[4], bl_[4];
    const int co = (lane >> 4) * 8;
    const int rr = lane & 15;
#pragma unroll
    for (int f = 0; f < 4; ++f) {
      const int ra = (wr * 64 + f * 16 + rr) * 32 + co;
      const uint4 p0 = *(const uint4*)&ldsA[ra];
      const uint4 p1 = *(const uint4*)&ldsA[ra + 4];
      BF8 hv, lv;
      uint32_t* hd = (uint32_t*)&hv.q4;
      uint32_t* ld = (uint32_t*)&lv.q4;
      hd[0] = __builtin_amdgcn_perm(p0.y, p0.x, 0x05040100u);
      hd[1] = __builtin_amdgcn_perm(p0.w, p0.z, 0x05040100u);
      hd[2] = __builtin_amdgcn_perm(p1.y, p1.x, 0x05040100u);
      hd[3] = __builtin_amdgcn_perm(p1.w, p1.z, 0x05040100u);
      ld[0] = __builtin_amdgcn_perm(p0.y, p0.x, 0x07060302u);
      ld[1] = __builtin_amdgcn_perm(p0.w, p0.z, 0x07060302u);
      ld[2] = __builtin_amdgcn_perm(p1.y, p1.x, 0x07060302u);
      ld[3] = __builtin_amdgcn_perm(p1.w, p1.z, 0x07060302u);
      ah[f] = hv.v; al[f] = lv.v;
      const int rb2 = (wcq * 64 + f * 16 + rr) * 32 + co;
      bh_[f] = *(const bf16x8*)&ldsBh[rb2];
      bl_[f] = *(const bf16x8*)&ldsBl[rb2];
    }
#pragma unroll
    for (int m = 0; m < 4; ++m)
#pragma unroll
      for (int n = 0; n < 4; ++n) {
        acc[m][n] = __builtin_amdgcn_mfma_f32_16x16x32_bf16(ah[m], bh_[n], acc[m][n], 0, 0, 0);
        acc[m][n] = __builtin_amdgcn_mfma_f32_16x16x32_bf16(ah[m], bl_[n], acc[m][n], 0, 0, 0);
        acc[m][n] = __builtin_amdgcn_mfma_f32_16x16x32_bf16(al[m], bh_[n], acc[m][n], 0, 0, 0);
      }
  }

  const int cn0 = lane & 15;
  const int rm0 = (lane >> 4) * 4;
#pragma unroll
  for (int n = 0; n < 4; ++n) {
    const int ng = bn * 128 + wcq * 64 + n * 16 + cn0;
    const float bv = bias[ng];
#pragma unroll
    for (int m = 0; m < 4; ++m) {
      const int mg = bm * 128 + wr * 64 + m * 16 + rm0;
#pragma unroll
      for (int r = 0; r < 4; ++r)
        C[(size_t)(mg + r) * 512 + ng] = acc[m][n][r] + bv;
    }
  }
}

// ---------------------------------------------------------------------------
// K2: MFMA routing; xp read PACKED (A-frags via v_perm). Per-wave LDS
// transpose -> coalesced packed u32 stores. Two __syncthreads per m-block:
// measured as live-range scissors (VGPR 68 vs 120 without; 175 vs 200 us).
// ---------------------------------------------------------------------------
__global__ __launch_bounds__(256, 4) void k2_route(
    const uint32_t* __restrict__ xpq, const float* __restrict__ Wsl,
    const float* __restrict__ bsl, const float* __restrict__ Wt1,
    const float* __restrict__ bt1, const float* __restrict__ Wt2,
    const float* __restrict__ bt2, const float* __restrict__ tbias,
    uint32_t* __restrict__ wcp)
{
  __shared__ u16 Wf[2][8][2][64][8];      // frag-ordered W planes, 32 KB
  __shared__ uint32_t wbuf[4][16][68];    // per-wave transpose, hi|lo<<16

  const int tid = threadIdx.x;
  const int l = tid & 63, wid = tid >> 6;
  const int l15 = l & 15, q = l >> 4;
  const int h = blockIdx.x >> 8;
  const int chunk = blockIdx.x & 255;

  // ---- stage W fragments (once per block) ----
#pragma unroll
  for (int it = 0; it < 8; ++it) {
    const int slot = tid + it * 256;
    const int p = slot >> 10;
    const int rest = slot & 1023;
    const int nn = rest >> 7;
    const int kk = (rest >> 6) & 1;
    const int sl = rest & 63;
    const int row = nn * 16 + (sl & 15);
    const int kb = kk * 32 + (sl >> 4) * 8;
    const float* src = (row < 64) ? (Wsl + row * 64 + kb)
                                  : (Wt1 + (row - 64) * 64 + kb);
#pragma unroll
    for (int e = 0; e < 8; ++e) {
      const float v = src[e];
      const u16 hb = f2bf(v);
      Wf[p][nn][kk][sl][e] = (p == 0) ? hb : f2bf(v - bf2f(hb));
    }
  }
  __syncthreads();

  float bslv[4], bt1v[4], wt2v[4];
#pragma unroll
  for (int j = 0; j < 4; ++j) {
    bslv[j] = bsl[j * 16 + l15];
    bt1v[j] = bt1[j * 16 + l15];
    wt2v[j] = Wt2[j * 16 + l15];
  }
  const float bt2v = bt2[0], tbv = tbias[h];

#pragma unroll 1
  for (int tm = 0; tm < 4; ++tm) {
    const int n0t = chunk * 256 + (tm >> 1) * 128 + wid * 32 + (tm & 1) * 16;

    // ---- A fragments from packed xp via v_perm ----
    bf16x8 ah[2], al[2];
#pragma unroll
    for (int kk = 0; kk < 2; ++kk) {
      const uint32_t* sp = xpq + (size_t)(n0t + l15) * 512 + h * 64
                           + kk * 32 + q * 8;
      const uint4 p0 = *(const uint4*)sp;
      const uint4 p1 = *(const uint4*)(sp + 4);
      BF8 hv, lv;
      uint32_t* hd = (uint32_t*)&hv.q4;
      uint32_t* ld = (uint32_t*)&lv.q4;
      hd[0] = __builtin_amdgcn_perm(p0.y, p0.x, 0x05040100u);
      hd[1] = __builtin_amdgcn_perm(p0.w, p0.z, 0x05040100u);
      hd[2] = __builtin_amdgcn_perm(p1.y, p1.x, 0x05040100u);
      hd[3] = __builtin_amdgcn_perm(p1.w, p1.z, 0x05040100u);
      ld[0] = __builtin_amdgcn_perm(p0.y, p0.x, 0x07060302u);
      ld[1] = __builtin_amdgcn_perm(p0.w, p0.z, 0x07060302u);
      ld[2] = __builtin_amdgcn_perm(p1.y, p1.x, 0x07060302u);
      ld[3] = __builtin_amdgcn_perm(p1.w, p1.z, 0x07060302u);
      ah[kk] = hv.v; al[kk] = lv.v;
    }

    // ---- MFMA: [16 tok] x [128 cols], K=64, 3-term ----
    f32x4 acc[8];
#pragma unroll
    for (int n = 0; n < 8; ++n) acc[n] = (f32x4){0.f, 0.f, 0.f, 0.f};
#pragma unroll
    for (int kk = 0; kk < 2; ++kk)
#pragma unroll
      for (int nn = 0; nn < 8; ++nn) {
        BF8 whf, wlf;
        whf.q4 = *(const uint4*)&Wf[0][nn][kk][l][0];
        wlf.q4 = *(const uint4*)&Wf[1][nn][kk][l][0];
        acc[nn] = __builtin_amdgcn_mfma_f32_16x16x32_bf16(ah[kk], whf.v, acc[nn], 0, 0, 0);
        acc[nn] = __builtin_amdgcn_mfma_f32_16x16x32_bf16(ah[kk], wlf.v, acc[nn], 0, 0, 0);
        acc[nn] = __builtin_amdgcn_mfma_f32_16x16x32_bf16(al[kk], whf.v, acc[nn], 0, 0, 0);
      }

    // ---- temperature per r ----
    float itv[4];
#pragma unroll
    for (int r = 0; r < 4; ++r) {
      float part = 0.f;
#pragma unroll
      for (int j = 0; j < 4; ++j)
        part += gelu_fast(acc[4 + j][r] + bt1v[j]) * wt2v[j];
      part += __shfl_xor(part, 1);
      part += __shfl_xor(part, 2);
      part += __shfl_xor(part, 4);
      part += __shfl_xor(part, 8);
      const float tval = gelu_fast(part + bt2v) + tbv;
      itv[r] = 1.0f / fmaxf(tval, 0.01f);
    }

    // ---- logits: bias + threefry-gumbel + /t ----
    const uint32_t pbase = ((uint32_t)((h << 16) | (n0t + q * 4))) << 6;
#pragma unroll
    for (int j = 0; j < 4; ++j) {
      const uint32_t cc = j * 16 + l15;
#pragma unroll
      for (int r = 0; r < 4; ++r) {
        const uint32_t bits = threefry_bits(pbase + ((uint32_t)r << 6) + cc);
        const float u = __uint_as_float((bits >> 9) | 0x3f800000u) - 1.0f;
        const float gin = -__logf(u + 1e-8f);
        const float gn = -__logf(gin + 1e-8f);
        acc[j][r] = (acc[j][r] + bslv[j] + gn) * itv[r];
      }
    }

    // ---- softmax over cols ----
#pragma unroll
    for (int r = 0; r < 4; ++r) {
      float mx = fmaxf(fmaxf(acc[0][r], acc[1][r]),
                       fmaxf(acc[2][r], acc[3][r]));
      mx = fmaxf(mx, __shfl_xor(mx, 1));
      mx = fmaxf(mx, __shfl_xor(mx, 2));
      mx = fmaxf(mx, __shfl_xor(mx, 4));
      mx = fmaxf(mx, __shfl_xor(mx, 8));
      float se = 0.f;
#pragma unroll
      for (int j = 0; j < 4; ++j) {
        const float e = __expf(acc[j][r] - mx);
        acc[j][r] = e;
        se += e;
      }
      se += __shfl_xor(se, 1);
      se += __shfl_xor(se, 2);
      se += __shfl_xor(se, 4);
      se += __shfl_xor(se, 8);
      const float inv = 1.0f / se;
#pragma unroll
      for (int j = 0; j < 4; ++j) acc[j][r] *= inv;
    }

    // ---- pack hi|lo into per-wave LDS transpose ----
#pragma unroll
    for (int j = 0; j < 4; ++j)
#pragma unroll
      for (int r = 0; r < 4; ++r) {
        const float wv = acc[j][r];
        const u16 hb = f2bf(wv);
        const u16 lb = f2bf(wv - bf2f(hb));
        wbuf[wid][q * 4 + r][j * 16 + l15] = (uint32_t)hb | ((uint32_t)lb << 16);
      }
    __syncthreads();

    // ---- coalesced packed stores: 16 tok x 16 uint4 -> 64 lanes x 4 ----
#pragma unroll
    for (int it = 0; it < 4; ++it) {
      const int t = l >> 2;
      const int qq = (l & 3) + it * 4;    // 0..15
      const uint4 v = *(const uint4*)&wbuf[wid][t][qq * 4];
      *(uint4*)(wcp + (size_t)(n0t + t) * 512 + h * 64 + qq * 4) = v;
    }
    __syncthreads();
  }
}

// ---------------------------------------------------------------------------
// K3: MFMA pooling. Per head: tok_num[g,d] = sum_n w[n,g]*x[n,d] (K=65536).
// Grid = 8 heads x 64 chunks (1024 tok); 4 waves x 256 tok; per wave 8 tiles
// of 32 tokens. Fragment gathers straight from global. 3-term split-bf16.
// ---------------------------------------------------------------------------
__global__ __launch_bounds__(256, 2) void k3_pool(
    const uint32_t* __restrict__ xpq, const uint32_t* __restrict__ wcp,
    float* __restrict__ tok_num, float* __restrict__ nrm)
{
  __shared__ float red[64][65];
  const int h = blockIdx.x >> 6;
  const int chunk = blockIdx.x & 63;
  const int lane = threadIdx.x & 63;
  const int wid = threadIdx.x >> 6;
  const int l15 = lane & 15, q = lane >> 4;

  f32x4 acc[4][4];
#pragma unroll
  for (int m = 0; m < 4; ++m)
#pragma unroll
    for (int n = 0; n < 4; ++n) acc[m][n] = (f32x4){0.f, 0.f, 0.f, 0.f};
  float csum[4] = {0.f, 0.f, 0.f, 0.f};

  const int tw = chunk * 1024 + wid * 256;
#pragma unroll 1
  for (int tt = 0; tt < 8; ++tt) {
    const int t0 = tw + tt * 32;
    uint32_t wreg[4][8], xreg[4][8];
#pragma unroll
    for (int e = 0; e < 8; ++e) {
      const size_t rb = (size_t)(t0 + q * 8 + e) * 512 + h * 64 + l15;
#pragma unroll
      for (int m = 0; m < 4; ++m) {
        wreg[m][e] = wcp[rb + m * 16];
        xreg[m][e] = xpq[rb + m * 16];
      }
    }
    bf16x8 whf[4], wlf[4], xhf[4], xlf[4];
#pragma unroll
    for (int m = 0; m < 4; ++m) {
      BF8 hv, lv, xh, xl;
      uint32_t* hd = (uint32_t*)&hv.q4;
      uint32_t* ld = (uint32_t*)&lv.q4;
      uint32_t* xhd = (uint32_t*)&xh.q4;
      uint32_t* xld = (uint32_t*)&xl.q4;
#pragma unroll
      for (int p = 0; p < 4; ++p) {
        hd[p]  = __builtin_amdgcn_perm(wreg[m][2*p+1], wreg[m][2*p], 0x05040100u);
        ld[p]  = __builtin_amdgcn_perm(wreg[m][2*p+1], wreg[m][2*p], 0x07060302u);
        xhd[p] = __builtin_amdgcn_perm(xreg[m][2*p+1], xreg[m][2*p], 0x05040100u);
        xld[p] = __builtin_amdgcn_perm(xreg[m][2*p+1], xreg[m][2*p], 0x07060302u);
      }
      whf[m] = hv.v; wlf[m] = lv.v; xhf[m] = xh.v; xlf[m] = xl.v;
#pragma unroll
      for (int e = 0; e < 8; ++e)
        csum[m] += __uint_as_float(wreg[m][e] << 16)
                 + __uint_as_float(wreg[m][e] & 0xffff0000u);
    }
#pragma unroll
    for (int m = 0; m < 4; ++m)
#pragma unroll
      for (int n = 0; n < 4; ++n) {
        acc[m][n] = __builtin_amdgcn_mfma_f32_16x16x32_bf16(whf[m], xhf[n], acc[m][n], 0, 0, 0);
        acc[m][n] = __builtin_amdgcn_mfma_f32_16x16x32_bf16(whf[m], xlf[n], acc[m][n], 0, 0, 0);
        acc[m][n] = __builtin_amdgcn_mfma_f32_16x16x32_bf16(wlf[m], xhf[n], acc[m][n], 0, 0, 0);
      }
  }

  // nrm: reduce csum over q-groups, lanes q==0 add 4 g-values each
#pragma unroll
  for (int m = 0; m < 4; ++m) {
    csum[m] += __shfl_xor(csum[m], 16);
    csum[m] += __shfl_xor(csum[m], 32);
  }
  if (q == 0) {
#pragma unroll
    for (int m = 0; m < 4; ++m)
      atomicAdd(&nrm[h * 64 + m * 16 + l15], csum[m]);
  }

  // cross-wave reduce
  for (int w = 0; w < 4; ++w) {
    if (wid == w) {
#pragma unroll
      for (int m = 0; m < 4; ++m)
#pragma unroll
        for (int n = 0; n < 4; ++n)
#pragma unroll
          for (int r = 0; r < 4; ++r) {
            const int g = m * 16 + q * 4 + r;
            const int d = n * 16 + l15;
            if (w == 0) red[g][d] = acc[m][n][r];
            else        red[g][d] += acc[m][n][r];
          }
    }
    __syncthreads();
  }
  for (int e = threadIdx.x; e < 4096; e += 256)
    atomicAdd(&tok_num[h * 4096 + e], red[e >> 6][e & 63]);
}

// ---------------------------------------------------------------------------
// K4a: per-head attention over G=64 slice tokens. One block per head.
// ---------------------------------------------------------------------------
__global__ __launch_bounds__(256) void k4_attn(
    const float* __restrict__ tok_num, const float* __restrict__ nrm,
    const float* __restrict__ Wq, const float* __restrict__ Wk,
    const float* __restrict__ Wv, const float* __restrict__ Wo,
    float* __restrict__ o_out)
{
  __shared__ float T[64][65], Abuf[64][65], Bbuf[64][65], Wbuf[64][65], S2[64][65];
  const int h = blockIdx.x;
  const int tid = threadIdx.x;

  for (int e = tid; e < 4096; e += 256) {
    const int g = e >> 6, d = e & 63;
    T[g][d] = tok_num[h * 4096 + e] / (nrm[h * 64 + g] + 1e-5f);
  }
  for (int e = tid; e < 4096; e += 256) Wbuf[e >> 6][e & 63] = Wq[e];
  __syncthreads();

  const int g = tid >> 2, d0 = (tid & 3) * 16;
  float r[16];

#pragma unroll
  for (int j = 0; j < 16; ++j) r[j] = 0.f;
  for (int e = 0; e < 64; ++e) {
    const float tv = T[g][e];
#pragma unroll
    for (int j = 0; j < 16; ++j) r[j] = fmaf(tv, Wbuf[d0 + j][e], r[j]);
  }
#pragma unroll
  for (int j = 0; j < 16; ++j) Abuf[g][d0 + j] = r[j];
  __syncthreads();

  for (int e = tid; e < 4096; e += 256) Wbuf[e >> 6][e & 63] = Wk[e];
  __syncthreads();

#pragma unroll
  for (int j = 0; j < 16; ++j) r[j] = 0.f;
  for (int e = 0; e < 64; ++e) {
    const float tv = T[g][e];
#pragma unroll
    for (int j = 0; j < 16; ++j) r[j] = fmaf(tv, Wbuf[d0 + j][e], r[j]);
  }
#pragma unroll
  for (int j = 0; j < 16; ++j) Bbuf[g][d0 + j] = r[j];
  __syncthreads();

#pragma unroll
  for (int j = 0; j < 16; ++j) r[j] = 0.f;
  for (int e = 0; e < 64; ++e) {
    const float qv = Abuf[g][e] * 0.125f;
#pragma unroll
    for (int j = 0; j < 16; ++j) r[j] = fmaf(qv, Bbuf[d0 + j][e], r[j]);
  }
#pragma unroll
  for (int j = 0; j < 16; ++j) S2[g][d0 + j] = r[j];
  __syncthreads();

  if (tid < 64) {
    float mx = -1e30f;
    for (int j = 0; j < 64; ++j) mx = fmaxf(mx, S2[tid][j]);
    float sum = 0.f;
    for (int j = 0; j < 64; ++j) {
      const float e2 = expf(S2[tid][j] - mx);
      S2[tid][j] = e2;
      sum += e2;
    }
    const float inv = 1.0f / sum;
    for (int j = 0; j < 64; ++j) S2[tid][j] *= inv;
  }
  __syncthreads();

  for (int e = tid; e < 4096; e += 256) Wbuf[e >> 6][e & 63] = Wv[e];
  __syncthreads();

#pragma unroll
  for (int j = 0; j < 16; ++j) r[j] = 0.f;
  for (int e = 0; e < 64; ++e) {
    const float tv = T[g][e];
#pragma unroll
    for (int j = 0; j < 16; ++j) r[j] = fmaf(tv, Wbuf[d0 + j][e], r[j]);
  }
  __syncthreads();
#pragma unroll
  for (int j = 0; j < 16; ++j) Bbuf[g][d0 + j] = r[j];
  __syncthreads();

#pragma unroll
  for (int j = 0; j < 16; ++j) r[j] = 0.f;
  for (int e = 0; e < 64; ++e) {
    const float sv = S2[g][e];
#pragma unroll
    for (int j = 0; j < 16; ++j) r[j] = fmaf(sv, Bbuf[e][d0 + j], r[j]);
  }
  __syncthreads();
#pragma unroll
  for (int j = 0; j < 16; ++j) Abuf[g][d0 + j] = r[j];
  for (int e = tid; e < 4096; e += 256) Wbuf[e >> 6][e & 63] = Wo[e];
  __syncthreads();

#pragma unroll
  for (int j = 0; j < 16; ++j) r[j] = 0.f;
  for (int e = 0; e < 64; ++e) {
    const float ov = Abuf[g][e];
#pragma unroll
    for (int j = 0; j < 16; ++j) r[j] = fmaf(ov, Wbuf[d0 + j][e], r[j]);
  }
#pragma unroll
  for (int j = 0; j < 16; ++j) o_out[h * 4096 + g * 64 + d0 + j] = r[j];
}

// ---------------------------------------------------------------------------
// K4b: M2T[j][hg] = sum_d o[hg][d] * W_out[j][h*64+d]  -> hi/lo bf16 planes
// ---------------------------------------------------------------------------
__global__ __launch_bounds__(256) void k4b_m2(
    const float* __restrict__ o, const float* __restrict__ Wout,
    u16* __restrict__ M2h, u16* __restrict__ M2l)
{
  const int j = blockIdx.x >> 1;
  const int hg = ((blockIdx.x & 1) << 8) + threadIdx.x;
  const int h = hg >> 6;
  const float* orow = &o[hg * 64];
  const float* wrow = &Wout[j * 512 + h * 64];
  float s = 0.f;
#pragma unroll
  for (int d = 0; d < 64; ++d) s = fmaf(orow[d], wrow[d], s);
  const u16 hb = f2bf(s);
  M2h[j * 512 + hg] = hb;
  M2l[j * 512 + hg] = f2bf(s - bf2f(hb));
}

// ---------------------------------------------------------------------------
extern "C" void kernel_launch(void* const* d_in, const int* in_sizes, int n_in,
                              void* d_out, int out_size, void* d_ws, size_t ws_size,
                              hipStream_t stream)
{
  const float* x      = (const float*)d_in[0];
  const float* W_x    = (const float*)d_in[1];
  const float* b_x    = (const float*)d_in[2];
  const float* W_sl   = (const float*)d_in[3];
  const float* b_sl   = (const float*)d_in[4];
  const float* W_t1   = (const float*)d_in[5];
  const float* b_t1   = (const float*)d_in[6];
  const float* W_t2   = (const float*)d_in[7];
  const float* b_t2   = (const float*)d_in[8];
  const float* t_bias = (const float*)d_in[9];
  const float* Wq     = (const float*)d_in[10];
  const float* Wk     = (const float*)d_in[11];
  const float* Wv     = (const float*)d_in[12];
  const float* Wo     = (const float*)d_in[13];
  const float* W_out  = (const float*)d_in[14];
  const float* b_out  = (const float*)d_in[15];

  float* out = (float*)d_out;
  uint32_t* xpq = (uint32_t*)d_out;  // packed xp lives in d_out until GEMM2

  char* ws = (char*)d_ws;
  u16*      Ahi   = (u16*)(ws);                  // x hi plane (GEMM1)
  u16*      Alo   = (u16*)(ws + 67108864);       // x lo plane (GEMM1)
  uint32_t* wcp   = (uint32_t*)(ws);             // packed wcat (after GEMM1)
  u16*      Bhi   = (u16*)(ws + 134217728);      // Wx hi, then M2T hi
  u16*      Blo   = (u16*)(ws + 134742016);      // Wx lo, then M2T lo
  float* tok_num  = (float*)(ws + 135266304);    // 131072 B
  float* nrm      = (float*)(ws + 135397376);    // 2048 B
  float* o_buf    = (float*)(ws + 135399424);    // 131072 B

  conv_split<<<2048, 256, 0, stream>>>(x, Ahi, Alo, 8388608);
  conv_split<<<256, 256, 0, stream>>>(W_x, Bhi, Blo, 65536);
  gemm_split<<<2048, 256, 0, stream>>>(Ahi, Alo, Bhi, Blo, b_x, xpq);

  hipMemsetAsync(tok_num, 0, 133120, stream);  // tok_num + nrm (contiguous)

  k2_route<<<2048, 256, 0, stream>>>(xpq, W_sl, b_sl, W_t1, b_t1, W_t2, b_t2,
                                     t_bias, wcp);
  k3_pool<<<512, 256, 0, stream>>>(xpq, wcp, tok_num, nrm);
  k4_attn<<<8, 256, 0, stream>>>(tok_num, nrm, Wq, Wk, Wv, Wo, o_buf);
  k4b_m2<<<1024, 256, 0, stream>>>(o_buf, W_out, Bhi, Blo);    // overwrites Wx-split
  gemm_packA<<<2048, 256, 0, stream>>>(wcp, Bhi, Blo, b_out, out);
}